// Round 3
// baseline (607.282 us; speedup 1.0000x reference)
//
#include <hip/hip_runtime.h>

// ---------------- problem constants ----------------
// x [8,3,512,512] -> conv1(4x4 s4)+relu -> h1 [8,64,128,128]
// -> conv2(4x4 s4)+bias -> h [8,128,32,32]
// -> 2x { r = conv3x3(relu(h)) [8,64,32,32]; h += conv1x1(relu(r)) }
// -> relu -> preq 1x1 + bias -> z_e [8,64,32,32]
// -> VQ against emb [1024,64]; outputs: loss, z_q [8,64,32,32], ppl, emb, idx
#define NPOS 8192           // 8*32*32 latent positions
#define ZQ_OFF   1
#define PPL_OFF  524289
#define EMB_OFF  524290
#define IDX_OFF  589826

// ---------------- conv1: 4x4 stride4, 3->64, +bias, relu ----------------
__global__ __launch_bounds__(256) void k_conv1(const float* __restrict__ x,
    const float* __restrict__ w, const float* __restrict__ bias,
    float* __restrict__ out) {
  int tid = blockIdx.x * 256 + threadIdx.x;      // 8*128*128 threads
  int ox = tid & 127, oy = (tid >> 7) & 127, b = tid >> 14;
  const float* xb = x + (size_t)b * 3 * 512 * 512 + (size_t)(oy * 4) * 512 + ox * 4;
  float p[48];
#pragma unroll
  for (int c = 0; c < 3; ++c)
#pragma unroll
    for (int ky = 0; ky < 4; ++ky) {
      float4 v = *(const float4*)(xb + ((size_t)c * 512 + ky) * 512);
      p[c*16+ky*4+0] = v.x; p[c*16+ky*4+1] = v.y;
      p[c*16+ky*4+2] = v.z; p[c*16+ky*4+3] = v.w;
    }
  float* ob = out + (size_t)b * 64 * 16384 + oy * 128 + ox;
  for (int oc = 0; oc < 64; oc += 4) {
    float a0 = bias[oc+0], a1 = bias[oc+1], a2 = bias[oc+2], a3 = bias[oc+3];
#pragma unroll
    for (int k = 0; k < 48; ++k) {
      float pk = p[k];
      a0 += w[(oc+0)*48+k] * pk;
      a1 += w[(oc+1)*48+k] * pk;
      a2 += w[(oc+2)*48+k] * pk;
      a3 += w[(oc+3)*48+k] * pk;
    }
    ob[(size_t)(oc+0)*16384] = fmaxf(a0, 0.f);
    ob[(size_t)(oc+1)*16384] = fmaxf(a1, 0.f);
    ob[(size_t)(oc+2)*16384] = fmaxf(a2, 0.f);
    ob[(size_t)(oc+3)*16384] = fmaxf(a3, 0.f);
  }
}

// ---------------- conv2: 4x4 stride4, 64->128, +bias (no relu) ----------------
// grid (ocg=2, oyp=16, b=8); block 256 = 4 waves; wave = 2 rows x 32 x; 16 oc/wave
__global__ __launch_bounds__(256) void k_conv2(const float* __restrict__ h1,
    const float* __restrict__ w, const float* __restrict__ bias,
    float* __restrict__ out) {
  __shared__ float lds[8][8][128];               // 8 ic x 8 rows x 128 px
  const int b = blockIdx.z, oyp = blockIdx.y, ocg = blockIdx.x;
  const int tid = threadIdx.x;
  const int lane = tid & 63;
  const int wv = __builtin_amdgcn_readfirstlane(tid >> 6);
  const int row = lane >> 5, ox = lane & 31;
  const int ocb = ocg * 64 + wv * 16;
  const float* src_base = h1 + ((size_t)b * 64 * 128 + (size_t)oyp * 8) * 128;
  float4 pre[8];
#define C2_LOAD(t) { \
    _Pragma("unroll") \
    for (int j = 0; j < 8; ++j) { \
      int idx4 = tid + j * 256; \
      int x4 = idx4 & 31, r = (idx4 >> 5) & 7, ic = idx4 >> 8; \
      pre[j] = *(const float4*)(src_base + (size_t)((t)*8+ic)*128*128 + r*128 + x4*4); \
    } }
  float acc[16];
#pragma unroll
  for (int j = 0; j < 16; ++j) acc[j] = bias[ocb + j];
  C2_LOAD(0)
  for (int t = 0; t < 8; ++t) {
    __syncthreads();
#pragma unroll
    for (int j = 0; j < 8; ++j) {
      int idx4 = tid + j * 256;
      int x4 = idx4 & 31, r = (idx4 >> 5) & 7, ic = idx4 >> 8;
      *(float4*)&lds[ic][r][x4*4] = pre[j];
    }
    __syncthreads();
    if (t < 7) C2_LOAD(t + 1)
    const int ic0 = t * 8;
    for (int i = 0; i < 8; ++i) {
#pragma unroll
      for (int ky = 0; ky < 4; ++ky) {
        float4 v = *(const float4*)&lds[i][row*4 + ky][ox*4];
        const float* wp = w + (size_t)ocb*1024 + (ic0+i)*16 + ky*4;
#pragma unroll
        for (int j = 0; j < 16; ++j) {
          const float* wj = wp + (size_t)j*1024;
          acc[j] += wj[0]*v.x + wj[1]*v.y + wj[2]*v.z + wj[3]*v.w;
        }
      }
    }
  }
  const int oy = oyp*2 + row;
  float* ob = out + ((size_t)b*128 + ocb)*1024 + oy*32 + ox;
#pragma unroll
  for (int j = 0; j < 16; ++j) ob[(size_t)j*1024] = acc[j];
}

// ---------------- res 3x3: r1 = conv3x3(relu(h)), 128->64, pad1 ----------------
// grid (ocg=2, yp=16, b=8); block 256 = 4 waves; wave = 2 rows x 32 x; 8 oc/wave
__global__ __launch_bounds__(256) void k_res3(const float* __restrict__ h,
    const float* __restrict__ w, float* __restrict__ r1) {
  __shared__ float lds[16][4][36];               // 16 ic x 4 rows x (34 px + pad)
  const int b = blockIdx.z, yp = blockIdx.y, ocg = blockIdx.x;
  const int tid = threadIdx.x;
  const int lane = tid & 63;
  const int wv = __builtin_amdgcn_readfirstlane(tid >> 6);
  const int row = lane >> 5, ox = lane & 31;
  const int ocb = ocg*32 + wv*8;
  float acc[8] = {0,0,0,0,0,0,0,0};
  const float* hb = h + (size_t)b*128*1024;
  // hoisted t-invariant staging decomposition (f -> xi, r, i, validity)
  int st_xi[9], st_r[9], st_i[9], st_y[9];
  bool st_ok[9];
#pragma unroll
  for (int it = 0; it < 9; ++it) {
    int f = tid + it*256;
    int xi = f % 36;
    int g = f / 36;                              // 0..63
    st_xi[it] = xi; st_r[it] = g & 3; st_i[it] = g >> 2;
    int y = yp*2 - 1 + (g & 3);
    st_y[it] = y;
    int xg = xi - 1;
    st_ok[it] = (xi < 34) && ((unsigned)y < 32u) && ((unsigned)xg < 32u);
  }
  for (int t = 0; t < 8; ++t) {
    const int ic0 = t*16;
    __syncthreads();
#pragma unroll
    for (int it = 0; it < 9; ++it) {             // 2304 slots / 256 threads
      float v = 0.f;
      if (st_ok[it])
        v = fmaxf(hb[(size_t)(ic0+st_i[it])*1024 + st_y[it]*32 + (st_xi[it]-1)], 0.f);
      lds[st_i[it]][st_r[it]][st_xi[it]] = v;
    }
    __syncthreads();
    for (int i = 0; i < 16; ++i) {
      float v0 = lds[i][row  ][ox], v1 = lds[i][row  ][ox+1], v2 = lds[i][row  ][ox+2];
      float v3 = lds[i][row+1][ox], v4 = lds[i][row+1][ox+1], v5 = lds[i][row+1][ox+2];
      float v6 = lds[i][row+2][ox], v7 = lds[i][row+2][ox+1], v8 = lds[i][row+2][ox+2];
      const float* wb = w + ((size_t)ocb*128 + (ic0+i))*9;
#pragma unroll
      for (int j = 0; j < 8; ++j) {
        const float* wj = wb + (size_t)j*1152;
        acc[j] += wj[0]*v0 + wj[1]*v1 + wj[2]*v2
                + wj[3]*v3 + wj[4]*v4 + wj[5]*v5
                + wj[6]*v6 + wj[7]*v7 + wj[8]*v8;
      }
    }
  }
  const int y = yp*2 + row;
  float* ob = r1 + ((size_t)b*64 + ocb)*1024 + y*32 + ox;
#pragma unroll
  for (int j = 0; j < 8; ++j) ob[(size_t)j*1024] = acc[j];
}

// ---------------- res 1x1: h += w2 @ relu(r1), 64->128 ----------------
// grid (pg=128, ocg=2); block 256 = 4 waves; wave = 64 positions; 16 oc/wave
__global__ __launch_bounds__(256) void k_res1(const float* __restrict__ r1,
    const float* __restrict__ w, float* __restrict__ h) {
  const int pg = blockIdx.x, ocg = blockIdx.y;
  const int tid = threadIdx.x, lane = tid & 63;
  const int wv = __builtin_amdgcn_readfirstlane(tid >> 6);
  const int p = pg*64 + lane;
  const int b = p >> 10, rem = p & 1023;
  const int ocb = ocg*64 + wv*16;
  const float* rb = r1 + (size_t)b*64*1024 + rem;
  float acc[16];
#pragma unroll
  for (int j = 0; j < 16; ++j) acc[j] = 0.f;
  for (int ic = 0; ic < 64; ++ic) {
    float rv = fmaxf(rb[(size_t)ic*1024], 0.f);
#pragma unroll
    for (int j = 0; j < 16; ++j) acc[j] += w[(size_t)(ocb+j)*64 + ic] * rv;
  }
  float* hb = h + ((size_t)b*128 + ocb)*1024 + rem;
#pragma unroll
  for (int j = 0; j < 16; ++j) hb[(size_t)j*1024] += acc[j];
}

// ---------------- preq: z_e = pw @ relu(h) + pb, 128->64 ----------------
// grid (pg=128, eg=2); block 256 = 4 waves; wave = 64 positions; 8 e/wave
__global__ __launch_bounds__(256) void k_preq(const float* __restrict__ h,
    const float* __restrict__ w, const float* __restrict__ bias,
    float* __restrict__ ze) {
  const int pg = blockIdx.x, eg = blockIdx.y;
  const int tid = threadIdx.x, lane = tid & 63;
  const int wv = __builtin_amdgcn_readfirstlane(tid >> 6);
  const int p = pg*64 + lane;
  const int b = p >> 10, rem = p & 1023;
  const int eb = eg*32 + wv*8;
  const float* hb = h + (size_t)b*128*1024 + rem;
  float acc[8];
#pragma unroll
  for (int j = 0; j < 8; ++j) acc[j] = 0.f;
  for (int ic = 0; ic < 128; ++ic) {
    float hv = fmaxf(hb[(size_t)ic*1024], 0.f);
#pragma unroll
    for (int j = 0; j < 8; ++j) acc[j] += w[(size_t)(eb+j)*128 + ic] * hv;
  }
#pragma unroll
  for (int j = 0; j < 8; ++j)
    ze[((size_t)b*64 + eb+j)*1024 + rem] = acc[j] + bias[eb+j];
}

// ---------------- e2[e] = ||emb_e||^2 ----------------
__global__ __launch_bounds__(256) void k_e2(const float* __restrict__ emb,
                                            float* __restrict__ e2) {
  int e = blockIdx.x*256 + threadIdx.x;          // 0..1023
  const float* er = emb + (size_t)e*64;
  float s = 0.f;
#pragma unroll
  for (int i = 0; i < 16; ++i) {
    float4 v = *(const float4*)(er + i*4);
    s += v.x*v.x + v.y*v.y + v.z*v.z + v.w*v.w;
  }
  e2[e] = s;
}

// ---------------- VQ distances + per-strip argmin ----------------
// grid 2048; block 256 = 4 waves; wave = 64 positions x strip of 16 codes
__global__ __launch_bounds__(256) void k_vq(const float* __restrict__ ze,
    const float* __restrict__ emb, const float* __restrict__ e2,
    float* __restrict__ part_d, int* __restrict__ part_i) {
  const int bid = blockIdx.x;
  const int sg = bid & 15, pg = bid >> 4;
  const int tid = threadIdx.x, lane = tid & 63;
  const int wv = __builtin_amdgcn_readfirstlane(tid >> 6);
  const int s = sg*4 + wv;                       // strip 0..63
  const int p = pg*64 + lane;
  const int b = p >> 10, rem = p & 1023;
  const float* zb = ze + (size_t)b*64*1024 + rem;
  float z[64];
#pragma unroll
  for (int i = 0; i < 64; ++i) z[i] = zb[(size_t)i*1024];
  float best = 3.4e38f; int bi = 0;
  const float* es = emb + (size_t)s*16*64;
  for (int j4 = 0; j4 < 16; j4 += 4) {
    float a0 = 0.f, a1 = 0.f, a2 = 0.f, a3 = 0.f;
#pragma unroll
    for (int i = 0; i < 64; ++i) {
      float zi = z[i];
      a0 += es[(j4+0)*64+i]*zi;
      a1 += es[(j4+1)*64+i]*zi;
      a2 += es[(j4+2)*64+i]*zi;
      a3 += es[(j4+3)*64+i]*zi;
    }
    float d0 = e2[s*16+j4+0] - 2.f*a0;
    float d1 = e2[s*16+j4+1] - 2.f*a1;
    float d2 = e2[s*16+j4+2] - 2.f*a2;
    float d3 = e2[s*16+j4+3] - 2.f*a3;
    if (d0 < best) { best = d0; bi = s*16+j4+0; }
    if (d1 < best) { best = d1; bi = s*16+j4+1; }
    if (d2 < best) { best = d2; bi = s*16+j4+2; }
    if (d3 < best) { best = d3; bi = s*16+j4+3; }
  }
  part_d[(size_t)s*NPOS + p] = best;
  part_i[(size_t)s*NPOS + p] = bi;
}

// ---------------- final argmin + z_q + loss partials + counts + idx ----------------
__global__ __launch_bounds__(256) void k_reduce(const float* __restrict__ part_d,
    const int* __restrict__ part_i, const float* __restrict__ emb,
    const float* __restrict__ ze, float* __restrict__ out,
    int* __restrict__ counts, float* __restrict__ sse) {
  const int p = blockIdx.x*256 + threadIdx.x;    // 0..8191
  float best = 3.4e38f; int id = 0;
  for (int s = 0; s < 64; ++s) {
    float d = part_d[(size_t)s*NPOS + p];
    int   i = part_i[(size_t)s*NPOS + p];
    if (d < best) { best = d; id = i; }
  }
  out[IDX_OFF + p] = (float)id;
  atomicAdd(&counts[id], 1);
  const int b = p >> 10, rem = p & 1023;
  const float* zb = ze + (size_t)b*64*1024 + rem;
  float* qo = out + ZQ_OFF + (size_t)b*64*1024 + rem;
  const float* er = emb + (size_t)id*64;
  float local = 0.f;
#pragma unroll
  for (int e4 = 0; e4 < 16; ++e4) {
    float4 q = *(const float4*)(er + e4*4);
    float z0 = zb[(size_t)(e4*4+0)*1024];
    float z1 = zb[(size_t)(e4*4+1)*1024];
    float z2 = zb[(size_t)(e4*4+2)*1024];
    float z3 = zb[(size_t)(e4*4+3)*1024];
    qo[(size_t)(e4*4+0)*1024] = q.x;
    qo[(size_t)(e4*4+1)*1024] = q.y;
    qo[(size_t)(e4*4+2)*1024] = q.z;
    qo[(size_t)(e4*4+3)*1024] = q.w;
    float d0 = q.x - z0, d1 = q.y - z1, d2 = q.z - z2, d3 = q.w - z3;
    local += d0*d0 + d1*d1 + d2*d2 + d3*d3;
  }
  for (int off = 32; off; off >>= 1) local += __shfl_down(local, off);
  if ((threadIdx.x & 63) == 0) atomicAdd(sse, local);
}

// ---------------- scalars: loss & perplexity ----------------
__global__ __launch_bounds__(256) void k_final(const int* __restrict__ counts,
    const float* __restrict__ sse, float* __restrict__ out) {
  __shared__ float red[4];
  float part = 0.f;
  for (int e = threadIdx.x; e < 1024; e += 256) {
    float pm = (float)counts[e] * (1.f/8192.f);
    part += pm * logf(pm + 1e-10f);
  }
  for (int off = 32; off; off >>= 1) part += __shfl_down(part, off);
  if ((threadIdx.x & 63) == 0) red[threadIdx.x >> 6] = part;
  __syncthreads();
  if (threadIdx.x == 0) {
    float t = red[0] + red[1] + red[2] + red[3];
    out[PPL_OFF] = expf(-t);
    out[0] = 1.25f * sse[0] * (1.f/524288.f);
  }
}

// ---------------- launcher ----------------
extern "C" void kernel_launch(void* const* d_in, const int* in_sizes, int n_in,
                              void* d_out, int out_size, void* d_ws, size_t ws_size,
                              hipStream_t stream) {
  (void)in_sizes; (void)n_in; (void)out_size; (void)ws_size;
  const float* x   = (const float*)d_in[0];
  const float* w1  = (const float*)d_in[1];
  const float* b1  = (const float*)d_in[2];
  const float* w2  = (const float*)d_in[3];
  const float* b2  = (const float*)d_in[4];
  const float* rw1 = (const float*)d_in[5];
  const float* rw2 = (const float*)d_in[6];
  const float* pw  = (const float*)d_in[7];
  const float* pb  = (const float*)d_in[8];
  const float* emb = (const float*)d_in[9];
  float* out = (float*)d_out;
  char* ws = (char*)d_ws;
  float* h1     = (float*)(ws);                    // 33,554,432 B
  float* h      = (float*)(ws + 33554432);         //  4,194,304 B
  float* r1     = (float*)(ws + 37748736);         //  2,097,152 B
  float* ze     = (float*)(ws + 39845888);         //  2,097,152 B
  float* e2     = (float*)(ws + 41943040);         //      4,096 B
  float* pd     = (float*)(ws + 41947136);         //  2,097,152 B
  int*   pi     = (int*)  (ws + 44044288);         //  2,097,152 B
  int*   counts = (int*)  (ws + 46141440);         //      4,096 B
  float* sse    = (float*)(ws + 46145536);         //          4 B

  hipMemsetAsync(counts, 0, 1024*4 + 4, stream);   // counts + sse
  k_conv1<<<512, 256, 0, stream>>>(x, w1, b1, h1);
  k_conv2<<<dim3(2,16,8), 256, 0, stream>>>(h1, w2, b2, h);
  for (int it = 0; it < 2; ++it) {                 // shared-weight residual stack
    k_res3<<<dim3(2,16,8), 256, 0, stream>>>(h, rw1, r1);
    k_res1<<<dim3(128,2), 256, 0, stream>>>(r1, rw2, h);
  }
  k_preq<<<dim3(128,2), 256, 0, stream>>>(h, pw, pb, ze);
  k_e2<<<4, 256, 0, stream>>>(emb, e2);
  k_vq<<<2048, 256, 0, stream>>>(ze, emb, e2, pd, pi);
  k_reduce<<<32, 256, 0, stream>>>(pd, pi, emb, ze, out, counts, sse);
  k_final<<<1, 256, 0, stream>>>(counts, sse, out);
  hipMemcpyAsync(out + EMB_OFF, emb, 65536*4, hipMemcpyDeviceToDevice, stream);
}

// Round 5
// 436.498 us; speedup vs baseline: 1.3913x; 1.3913x over previous
//
#include <hip/hip_runtime.h>

// ---------------- problem constants ----------------
// x [8,3,512,512] -> conv1(4x4 s4)+relu -> h1 [8,64,128,128]
// -> conv2(4x4 s4)+bias -> h [8,128,32,32]   (implicit-GEMM, K-split x2)
// -> 2x { r = conv3x3(relu(h)) [8,64,32,32]; h += conv1x1(relu(r)) }
// -> relu -> preq 1x1 + bias -> z_e [8,64,32,32]
// -> VQ against emb [1024,64]; outputs: loss, z_q [8,64,32,32], ppl, emb, idx
#define NPOS 8192           // 8*32*32 latent positions
#define ZQ_OFF   1
#define PPL_OFF  524289
#define EMB_OFF  524290
#define IDX_OFF  589826

// ---------------- conv1: 4x4 stride4, 3->64, +bias, relu ----------------
__global__ __launch_bounds__(256) void k_conv1(const float* __restrict__ x,
    const float* __restrict__ w, const float* __restrict__ bias,
    float* __restrict__ out) {
  int tid = blockIdx.x * 256 + threadIdx.x;      // 8*128*128 threads
  int ox = tid & 127, oy = (tid >> 7) & 127, b = tid >> 14;
  const float* xb = x + (size_t)b * 3 * 512 * 512 + (size_t)(oy * 4) * 512 + ox * 4;
  float p[48];
#pragma unroll
  for (int c = 0; c < 3; ++c)
#pragma unroll
    for (int ky = 0; ky < 4; ++ky) {
      float4 v = *(const float4*)(xb + ((size_t)c * 512 + ky) * 512);
      p[c*16+ky*4+0] = v.x; p[c*16+ky*4+1] = v.y;
      p[c*16+ky*4+2] = v.z; p[c*16+ky*4+3] = v.w;
    }
  float* ob = out + (size_t)b * 64 * 16384 + oy * 128 + ox;
  for (int oc = 0; oc < 64; oc += 4) {
    float a0 = bias[oc+0], a1 = bias[oc+1], a2 = bias[oc+2], a3 = bias[oc+3];
#pragma unroll
    for (int k = 0; k < 48; ++k) {
      float pk = p[k];
      a0 += w[(oc+0)*48+k] * pk;
      a1 += w[(oc+1)*48+k] * pk;
      a2 += w[(oc+2)*48+k] * pk;
      a3 += w[(oc+3)*48+k] * pk;
    }
    ob[(size_t)(oc+0)*16384] = fmaxf(a0, 0.f);
    ob[(size_t)(oc+1)*16384] = fmaxf(a1, 0.f);
    ob[(size_t)(oc+2)*16384] = fmaxf(a2, 0.f);
    ob[(size_t)(oc+3)*16384] = fmaxf(a3, 0.f);
  }
}

// ---------------- conv2 (implicit GEMM, K-split) ----------------
// grid (x: kc2 | ocg2 = 4, y: pg16, z: b8) = 512 blocks; 256 thr = 4 waves.
// block tile: 64 pos (2 out rows) x 64 oc x K-chunk 512 (32 ic), t-loop 4 x 8 ic.
// LDS: im2col A [128k][64pos] 32KB + B [128k][64oc] 32KB -> 2 blocks/CU.
// stride4/kernel4: im2col is a perfect partition -> conflict-free 4-way scatter.
__global__ __launch_bounds__(256) void k_conv2p(const float* __restrict__ h1,
    const float* __restrict__ w, float* __restrict__ pd) {
  __shared__ float Asm[128*64];
  __shared__ float Bsm[128*64];
  const int b = blockIdx.z, pg = blockIdx.y;
  const int kc = blockIdx.x & 1, ocg = blockIdx.x >> 1;
  const int tid = threadIdx.x;
  const int lane = tid & 63;
  const int wv = __builtin_amdgcn_readfirstlane(tid >> 6);
  const int ox = lane & 31, og = lane >> 5;
  float4 pa[8], pb[8];
  const float* srcA = h1 + ((size_t)(b*64 + kc*32)) * 16384 + (size_t)(pg*8) * 128;
  const float* srcB = w + (size_t)(ocg*64) * 1024 + kc*512;
#define C2P_LOAD(t) { \
    _Pragma("unroll") \
    for (int j = 0; j < 8; ++j) { \
      int f = tid + j*256; \
      int x4 = f & 31, r = (f>>5) & 7, i = f >> 8; \
      pa[j] = *(const float4*)(srcA + (size_t)((t)*8 + i)*16384 + r*128 + x4*4); \
      int oc = f & 63, kq = f >> 6; \
      pb[j] = *(const float4*)(srcB + (size_t)oc*1024 + (t)*128 + kq*4); \
    } }
  C2P_LOAD(0)
  float acc0[8] = {0,0,0,0,0,0,0,0};
  float acc1[8] = {0,0,0,0,0,0,0,0};
  const float* ap = &Asm[ox];
  const float* bp = &Bsm[wv*16 + og*8];
  for (int t = 0; t < 4; ++t) {
    __syncthreads();
#pragma unroll
    for (int j = 0; j < 8; ++j) {
      int f = tid + j*256;
      int x4 = f & 31, r = (f>>5) & 7, i = f >> 8;
      int k0 = i*16 + (r&3)*4, pos = (r>>2)*32 + x4;   // ky=r&3, oyL=r>>2, kx=delta
      Asm[(k0+0)*64+pos] = pa[j].x;
      Asm[(k0+1)*64+pos] = pa[j].y;
      Asm[(k0+2)*64+pos] = pa[j].z;
      Asm[(k0+3)*64+pos] = pa[j].w;
      int oc = f & 63, kq = f >> 6;
      Bsm[(kq*4+0)*64+oc] = pb[j].x;
      Bsm[(kq*4+1)*64+oc] = pb[j].y;
      Bsm[(kq*4+2)*64+oc] = pb[j].z;
      Bsm[(kq*4+3)*64+oc] = pb[j].w;
    }
    __syncthreads();
    if (t < 3) C2P_LOAD(t+1)
#pragma unroll 8
    for (int k = 0; k < 128; ++k) {
      float a0 = ap[k*64];                 // pos (oyL=0, ox)
      float a1 = ap[k*64+32];              // pos (oyL=1, ox)  -> ds_read2
      float4 b0 = *(const float4*)&bp[k*64];
      float4 b1 = *(const float4*)&bp[k*64+4];
      acc0[0] += a0*b0.x; acc0[1] += a0*b0.y; acc0[2] += a0*b0.z; acc0[3] += a0*b0.w;
      acc0[4] += a0*b1.x; acc0[5] += a0*b1.y; acc0[6] += a0*b1.z; acc0[7] += a0*b1.w;
      acc1[0] += a1*b0.x; acc1[1] += a1*b0.y; acc1[2] += a1*b0.z; acc1[3] += a1*b0.w;
      acc1[4] += a1*b1.x; acc1[5] += a1*b1.y; acc1[6] += a1*b1.z; acc1[7] += a1*b1.w;
    }
  }
  const int ocb = ocg*64 + wv*16 + og*8;
  float* o0 = pd + (size_t)kc*1048576 + ((size_t)b*128 + ocb)*1024 + (pg*2)*32 + ox;
  float* o1 = o0 + 32;
#pragma unroll
  for (int j = 0; j < 8; ++j) {
    o0[(size_t)j*1024] = acc0[j];
    o1[(size_t)j*1024] = acc1[j];
  }
}

// ---------------- conv2 partial reduce: h = bias + p0 + p1 ----------------
__global__ __launch_bounds__(256) void k_c2red(const float* __restrict__ pd,
    const float* __restrict__ bias, float* __restrict__ h) {
  int i4 = blockIdx.x*256 + threadIdx.x;       // 0..262143 float4s
  int oc = (i4 >> 8) & 127;                    // (i4*4)>>10
  float bv = bias[oc];
  const float4 p0 = ((const float4*)pd)[i4];
  const float4 p1 = ((const float4*)pd)[i4 + 262144];
  float4 r;
  r.x = bv + p0.x + p1.x; r.y = bv + p0.y + p1.y;
  r.z = bv + p0.z + p1.z; r.w = bv + p0.w + p1.w;
  ((float4*)h)[i4] = r;
}

// ---------------- res 3x3: r1 = conv3x3(relu(h)), 128->64, pad1 ----------------
// grid (ocg=2, yp=16, b=8); block 256 = 4 waves; wave = 2 rows x 32 x; 8 oc/wave
__global__ __launch_bounds__(256) void k_res3(const float* __restrict__ h,
    const float* __restrict__ w, float* __restrict__ r1) {
  __shared__ float lds[16][4][36];               // 16 ic x 4 rows x (34 px + pad)
  const int b = blockIdx.z, yp = blockIdx.y, ocg = blockIdx.x;
  const int tid = threadIdx.x;
  const int lane = tid & 63;
  const int wv = __builtin_amdgcn_readfirstlane(tid >> 6);
  const int row = lane >> 5, ox = lane & 31;
  const int ocb = ocg*32 + wv*8;
  float acc[8] = {0,0,0,0,0,0,0,0};
  const float* hb = h + (size_t)b*128*1024;
  int st_xi[9], st_r[9], st_i[9], st_y[9];
  bool st_ok[9];
#pragma unroll
  for (int it = 0; it < 9; ++it) {
    int f = tid + it*256;
    int xi = f % 36;
    int g = f / 36;                              // 0..63
    st_xi[it] = xi; st_r[it] = g & 3; st_i[it] = g >> 2;
    int y = yp*2 - 1 + (g & 3);
    st_y[it] = y;
    int xg = xi - 1;
    st_ok[it] = (xi < 34) && ((unsigned)y < 32u) && ((unsigned)xg < 32u);
  }
  for (int t = 0; t < 8; ++t) {
    const int ic0 = t*16;
    __syncthreads();
#pragma unroll
    for (int it = 0; it < 9; ++it) {             // 2304 slots / 256 threads
      float v = 0.f;
      if (st_ok[it])
        v = fmaxf(hb[(size_t)(ic0+st_i[it])*1024 + st_y[it]*32 + (st_xi[it]-1)], 0.f);
      lds[st_i[it]][st_r[it]][st_xi[it]] = v;
    }
    __syncthreads();
    for (int i = 0; i < 16; ++i) {
      float v0 = lds[i][row  ][ox], v1 = lds[i][row  ][ox+1], v2 = lds[i][row  ][ox+2];
      float v3 = lds[i][row+1][ox], v4 = lds[i][row+1][ox+1], v5 = lds[i][row+1][ox+2];
      float v6 = lds[i][row+2][ox], v7 = lds[i][row+2][ox+1], v8 = lds[i][row+2][ox+2];
      const float* wb = w + ((size_t)ocb*128 + (ic0+i))*9;
#pragma unroll
      for (int j = 0; j < 8; ++j) {
        const float* wj = wb + (size_t)j*1152;
        acc[j] += wj[0]*v0 + wj[1]*v1 + wj[2]*v2
                + wj[3]*v3 + wj[4]*v4 + wj[5]*v5
                + wj[6]*v6 + wj[7]*v7 + wj[8]*v8;
      }
    }
  }
  const int y = yp*2 + row;
  float* ob = r1 + ((size_t)b*64 + ocb)*1024 + y*32 + ox;
#pragma unroll
  for (int j = 0; j < 8; ++j) ob[(size_t)j*1024] = acc[j];
}

// ---------------- res 1x1: h += w2 @ relu(r1), 64->128 ----------------
__global__ __launch_bounds__(256) void k_res1(const float* __restrict__ r1,
    const float* __restrict__ w, float* __restrict__ h) {
  const int pg = blockIdx.x, ocg = blockIdx.y;
  const int tid = threadIdx.x, lane = tid & 63;
  const int wv = __builtin_amdgcn_readfirstlane(tid >> 6);
  const int p = pg*64 + lane;
  const int b = p >> 10, rem = p & 1023;
  const int ocb = ocg*64 + wv*16;
  const float* rb = r1 + (size_t)b*64*1024 + rem;
  float acc[16];
#pragma unroll
  for (int j = 0; j < 16; ++j) acc[j] = 0.f;
  for (int ic = 0; ic < 64; ++ic) {
    float rv = fmaxf(rb[(size_t)ic*1024], 0.f);
#pragma unroll
    for (int j = 0; j < 16; ++j) acc[j] += w[(size_t)(ocb+j)*64 + ic] * rv;
  }
  float* hb = h + ((size_t)b*128 + ocb)*1024 + rem;
#pragma unroll
  for (int j = 0; j < 16; ++j) hb[(size_t)j*1024] += acc[j];
}

// ---------------- preq: z_e = pw @ relu(h) + pb, 128->64 ----------------
__global__ __launch_bounds__(256) void k_preq(const float* __restrict__ h,
    const float* __restrict__ w, const float* __restrict__ bias,
    float* __restrict__ ze) {
  const int pg = blockIdx.x, eg = blockIdx.y;
  const int tid = threadIdx.x, lane = tid & 63;
  const int wv = __builtin_amdgcn_readfirstlane(tid >> 6);
  const int p = pg*64 + lane;
  const int b = p >> 10, rem = p & 1023;
  const int eb = eg*32 + wv*8;
  const float* hb = h + (size_t)b*128*1024 + rem;
  float acc[8];
#pragma unroll
  for (int j = 0; j < 8; ++j) acc[j] = 0.f;
  for (int ic = 0; ic < 128; ++ic) {
    float hv = fmaxf(hb[(size_t)ic*1024], 0.f);
#pragma unroll
    for (int j = 0; j < 8; ++j) acc[j] += w[(size_t)(eb+j)*128 + ic] * hv;
  }
#pragma unroll
  for (int j = 0; j < 8; ++j)
    ze[((size_t)b*64 + eb+j)*1024 + rem] = acc[j] + bias[eb+j];
}

// ---------------- e2[e] = ||emb_e||^2 ----------------
__global__ __launch_bounds__(256) void k_e2(const float* __restrict__ emb,
                                            float* __restrict__ e2) {
  int e = blockIdx.x*256 + threadIdx.x;          // 0..1023
  const float* er = emb + (size_t)e*64;
  float s = 0.f;
#pragma unroll
  for (int i = 0; i < 16; ++i) {
    float4 v = *(const float4*)(er + i*4);
    s += v.x*v.x + v.y*v.y + v.z*v.z + v.w*v.w;
  }
  e2[e] = s;
}

// ---------------- VQ distances + per-strip argmin ----------------
__global__ __launch_bounds__(256) void k_vq(const float* __restrict__ ze,
    const float* __restrict__ emb, const float* __restrict__ e2,
    float* __restrict__ part_d, int* __restrict__ part_i) {
  const int bid = blockIdx.x;
  const int sg = bid & 15, pg = bid >> 4;
  const int tid = threadIdx.x, lane = tid & 63;
  const int wv = __builtin_amdgcn_readfirstlane(tid >> 6);
  const int s = sg*4 + wv;                       // strip 0..63
  const int p = pg*64 + lane;
  const int b = p >> 10, rem = p & 1023;
  const float* zb = ze + (size_t)b*64*1024 + rem;
  float z[64];
#pragma unroll
  for (int i = 0; i < 64; ++i) z[i] = zb[(size_t)i*1024];
  float best = 3.4e38f; int bi = 0;
  const float* es = emb + (size_t)s*16*64;
  for (int j4 = 0; j4 < 16; j4 += 4) {
    float a0 = 0.f, a1 = 0.f, a2 = 0.f, a3 = 0.f;
#pragma unroll
    for (int i = 0; i < 64; ++i) {
      float zi = z[i];
      a0 += es[(j4+0)*64+i]*zi;
      a1 += es[(j4+1)*64+i]*zi;
      a2 += es[(j4+2)*64+i]*zi;
      a3 += es[(j4+3)*64+i]*zi;
    }
    float d0 = e2[s*16+j4+0] - 2.f*a0;
    float d1 = e2[s*16+j4+1] - 2.f*a1;
    float d2 = e2[s*16+j4+2] - 2.f*a2;
    float d3 = e2[s*16+j4+3] - 2.f*a3;
    if (d0 < best) { best = d0; bi = s*16+j4+0; }
    if (d1 < best) { best = d1; bi = s*16+j4+1; }
    if (d2 < best) { best = d2; bi = s*16+j4+2; }
    if (d3 < best) { best = d3; bi = s*16+j4+3; }
  }
  part_d[(size_t)s*NPOS + p] = best;
  part_i[(size_t)s*NPOS + p] = bi;
}

// ---------------- final argmin + z_q + loss partials + counts + idx ----------------
__global__ __launch_bounds__(256) void k_reduce(const float* __restrict__ part_d,
    const int* __restrict__ part_i, const float* __restrict__ emb,
    const float* __restrict__ ze, float* __restrict__ out,
    int* __restrict__ counts, float* __restrict__ sse) {
  const int p = blockIdx.x*256 + threadIdx.x;    // 0..8191
  float best = 3.4e38f; int id = 0;
  for (int s = 0; s < 64; ++s) {
    float d = part_d[(size_t)s*NPOS + p];
    int   i = part_i[(size_t)s*NPOS + p];
    if (d < best) { best = d; id = i; }
  }
  out[IDX_OFF + p] = (float)id;
  atomicAdd(&counts[id], 1);
  const int b = p >> 10, rem = p & 1023;
  const float* zb = ze + (size_t)b*64*1024 + rem;
  float* qo = out + ZQ_OFF + (size_t)b*64*1024 + rem;
  const float* er = emb + (size_t)id*64;
  float local = 0.f;
#pragma unroll
  for (int e4 = 0; e4 < 16; ++e4) {
    float4 q = *(const float4*)(er + e4*4);
    float z0 = zb[(size_t)(e4*4+0)*1024];
    float z1 = zb[(size_t)(e4*4+1)*1024];
    float z2 = zb[(size_t)(e4*4+2)*1024];
    float z3 = zb[(size_t)(e4*4+3)*1024];
    qo[(size_t)(e4*4+0)*1024] = q.x;
    qo[(size_t)(e4*4+1)*1024] = q.y;
    qo[(size_t)(e4*4+2)*1024] = q.z;
    qo[(size_t)(e4*4+3)*1024] = q.w;
    float d0 = q.x - z0, d1 = q.y - z1, d2 = q.z - z2, d3 = q.w - z3;
    local += d0*d0 + d1*d1 + d2*d2 + d3*d3;
  }
  for (int off = 32; off; off >>= 1) local += __shfl_down(local, off);
  if ((threadIdx.x & 63) == 0) atomicAdd(sse, local);
}

// ---------------- scalars: loss & perplexity ----------------
__global__ __launch_bounds__(256) void k_final(const int* __restrict__ counts,
    const float* __restrict__ sse, float* __restrict__ out) {
  __shared__ float red[4];
  float part = 0.f;
  for (int e = threadIdx.x; e < 1024; e += 256) {
    float pm = (float)counts[e] * (1.f/8192.f);
    part += pm * logf(pm + 1e-10f);
  }
  for (int off = 32; off; off >>= 1) part += __shfl_down(part, off);
  if ((threadIdx.x & 63) == 0) red[threadIdx.x >> 6] = part;
  __syncthreads();
  if (threadIdx.x == 0) {
    float t = red[0] + red[1] + red[2] + red[3];
    out[PPL_OFF] = expf(-t);
    out[0] = 1.25f * sse[0] * (1.f/524288.f);
  }
}

// ---------------- launcher ----------------
extern "C" void kernel_launch(void* const* d_in, const int* in_sizes, int n_in,
                              void* d_out, int out_size, void* d_ws, size_t ws_size,
                              hipStream_t stream) {
  (void)in_sizes; (void)n_in; (void)out_size; (void)ws_size;
  const float* x   = (const float*)d_in[0];
  const float* w1  = (const float*)d_in[1];
  const float* b1  = (const float*)d_in[2];
  const float* w2  = (const float*)d_in[3];
  const float* b2  = (const float*)d_in[4];
  const float* rw1 = (const float*)d_in[5];
  const float* rw2 = (const float*)d_in[6];
  const float* pw  = (const float*)d_in[7];
  const float* pb  = (const float*)d_in[8];
  const float* emb = (const float*)d_in[9];
  float* out = (float*)d_out;
  char* ws = (char*)d_ws;
  // layout (bytes) — total 46,145,540, identical footprint to passing round:
  float* h1     = (float*)(ws);                    // 0        .. 33,554,432
  float* c2pd   = (float*)(ws + 33554432);         // 8 MB partials (dead after c2red)
  float* h      = (float*)(ws + 41943040);         // 4 MB
  float* r1     = (float*)(ws + 33554432);         // 2 MB (reuse of c2pd region)
  float* ze     = (float*)(ws + 35651584);         // 2 MB
  float* pd     = (float*)(ws + 37748736);         // 2 MB (VQ partial dist)
  int*   pi     = (int*)  (ws + 39845888);         // 2 MB (VQ partial idx)
  float* e2     = (float*)(ws + 46137344);         // 4 KB
  int*   counts = (int*)  (ws + 46141440);         // 4 KB
  float* sse    = (float*)(ws + 46145536);         // 4 B

  hipMemsetAsync(counts, 0, 1024*4 + 4, stream);   // counts + sse
  k_conv1<<<512, 256, 0, stream>>>(x, w1, b1, h1);
  k_conv2p<<<dim3(4,16,8), 256, 0, stream>>>(h1, w2, c2pd);
  k_c2red<<<1024, 256, 0, stream>>>(c2pd, b2, h);
  for (int it = 0; it < 2; ++it) {                 // shared-weight residual stack
    k_res3<<<dim3(2,16,8), 256, 0, stream>>>(h, rw1, r1);
    k_res1<<<dim3(128,2), 256, 0, stream>>>(r1, rw2, h);
  }
  k_preq<<<dim3(128,2), 256, 0, stream>>>(h, pw, pb, ze);
  k_e2<<<4, 256, 0, stream>>>(emb, e2);
  k_vq<<<2048, 256, 0, stream>>>(ze, emb, e2, pd, pi);
  k_reduce<<<32, 256, 0, stream>>>(pd, pi, emb, ze, out, counts, sse);
  k_final<<<1, 256, 0, stream>>>(counts, sse, out);
  hipMemcpyAsync(out + EMB_OFF, emb, 65536*4, hipMemcpyDeviceToDevice, stream);
}

// Round 7
// 341.515 us; speedup vs baseline: 1.7782x; 1.2781x over previous
//
#include <hip/hip_runtime.h>

// ---------------- problem constants ----------------
// x [8,3,512,512] -> conv1(4x4 s4)+relu -> h1 [8,64,128,128]    (GEMM, LDS A+B)
// -> conv2(4x4 s4)+bias -> h [8,128,32,32]                      (GEMM, K-split x2)
// -> 2x { r = conv3x3(relu(h)) [8,64,32,32]; h += conv1x1(relu(r)) }  (GEMM, kc x4)
// -> relu -> preq 1x1 + bias -> z_e [8,64,32,32]
// -> VQ against emb [1024,64]; outputs: loss, z_q [8,64,32,32], ppl, emb, idx
#define NPOS 8192
#define ZQ_OFF   1
#define PPL_OFF  524289
#define EMB_OFF  524290
#define IDX_OFF  589826

// ---------------- conv1 as implicit GEMM: K=48, tile 64pos x 64oc ----------------
// grid (xh2, oy128, b8) = 2048 blocks; thread = 2 pos x 8 oc. No s_load in loop.
__global__ __launch_bounds__(256) void k_conv1(const float* __restrict__ x,
    const float* __restrict__ w, const float* __restrict__ bias,
    float* __restrict__ out) {
  __shared__ float A[48*64];
  __shared__ float B[48*64];
  const int b = blockIdx.z, oy = blockIdx.y, xh = blockIdx.x;
  const int tid = threadIdx.x, lane = tid & 63;
  const int wv = __builtin_amdgcn_readfirstlane(tid >> 6);
  const int col = lane & 31, og = lane >> 5;
  const float* xb = x + (size_t)b*786432 + (size_t)(oy*4)*512 + xh*256;
#pragma unroll
  for (int j = 0; j < 3; ++j) {                  // A: [k=c*16+iy*4+ix][pos]
    int f = tid + j*256;                         // 768 float4s
    int c = f >> 8, iy = (f >> 6) & 3, x4 = f & 63;
    float4 v = *(const float4*)(xb + (size_t)c*262144 + (size_t)iy*512 + x4*4);
    int k0 = c*16 + iy*4;
    A[(k0+0)*64 + x4] = v.x;
    A[(k0+1)*64 + x4] = v.y;
    A[(k0+2)*64 + x4] = v.z;
    A[(k0+3)*64 + x4] = v.w;
  }
#pragma unroll
  for (int j = 0; j < 3; ++j) {                  // B: w[oc][48] -> B[k][oc]
    int fi = tid + j*256;
    float4 v = ((const float4*)w)[fi];
    int base = fi*4;
#pragma unroll
    for (int e = 0; e < 4; ++e) {
      int f = base + e;
      int oc = f / 48, k = f - oc*48;
      B[k*64 + oc] = (&v.x)[e];
    }
  }
  __syncthreads();
  const int ocb = wv*16 + og*8;
  float acc0[8], acc1[8];
#pragma unroll
  for (int j = 0; j < 8; ++j) { acc0[j] = bias[ocb+j]; acc1[j] = acc0[j]; }
  const float* ap = A + col;
  const float* bp = B + ocb;
#pragma unroll 8
  for (int k = 0; k < 48; ++k) {
    float a0 = ap[k*64];
    float a1 = ap[k*64 + 32];
    float4 b0 = *(const float4*)(bp + k*64);
    float4 b1 = *(const float4*)(bp + k*64 + 4);
    acc0[0] += a0*b0.x; acc0[1] += a0*b0.y; acc0[2] += a0*b0.z; acc0[3] += a0*b0.w;
    acc0[4] += a0*b1.x; acc0[5] += a0*b1.y; acc0[6] += a0*b1.z; acc0[7] += a0*b1.w;
    acc1[0] += a1*b0.x; acc1[1] += a1*b0.y; acc1[2] += a1*b0.z; acc1[3] += a1*b0.w;
    acc1[4] += a1*b1.x; acc1[5] += a1*b1.y; acc1[6] += a1*b1.z; acc1[7] += a1*b1.w;
  }
  float* ob = out + ((size_t)(b*64 + ocb))*16384 + oy*128 + xh*64 + col;
#pragma unroll
  for (int j = 0; j < 8; ++j) {
    ob[(size_t)j*16384]      = fmaxf(acc0[j], 0.f);
    ob[(size_t)j*16384 + 32] = fmaxf(acc1[j], 0.f);
  }
}

// ---------------- conv2 (implicit GEMM, K-split x2) — unchanged ----------------
__global__ __launch_bounds__(256) void k_conv2p(const float* __restrict__ h1,
    const float* __restrict__ w, float* __restrict__ pd) {
  __shared__ float Asm[128*64];
  __shared__ float Bsm[128*64];
  const int b = blockIdx.z, pg = blockIdx.y;
  const int kc = blockIdx.x & 1, ocg = blockIdx.x >> 1;
  const int tid = threadIdx.x;
  const int lane = tid & 63;
  const int wv = __builtin_amdgcn_readfirstlane(tid >> 6);
  const int ox = lane & 31, og = lane >> 5;
  float4 pa[8], pb[8];
  const float* srcA = h1 + ((size_t)(b*64 + kc*32)) * 16384 + (size_t)(pg*8) * 128;
  const float* srcB = w + (size_t)(ocg*64) * 1024 + kc*512;
#define C2P_LOAD(t) { \
    _Pragma("unroll") \
    for (int j = 0; j < 8; ++j) { \
      int f = tid + j*256; \
      int x4 = f & 31, r = (f>>5) & 7, i = f >> 8; \
      pa[j] = *(const float4*)(srcA + (size_t)((t)*8+i)*16384 + r*128 + x4*4); \
      int oc = f & 63, kq = f >> 6; \
      pb[j] = *(const float4*)(srcB + (size_t)oc*1024 + (t)*128 + kq*4); \
    } }
  C2P_LOAD(0)
  float acc0[8] = {0,0,0,0,0,0,0,0};
  float acc1[8] = {0,0,0,0,0,0,0,0};
  const float* ap = &Asm[ox];
  const float* bp = &Bsm[wv*16 + og*8];
  for (int t = 0; t < 4; ++t) {
    __syncthreads();
#pragma unroll
    for (int j = 0; j < 8; ++j) {
      int f = tid + j*256;
      int x4 = f & 31, r = (f>>5) & 7, i = f >> 8;
      int k0 = i*16 + (r&3)*4, pos = (r>>2)*32 + x4;
      Asm[(k0+0)*64+pos] = pa[j].x;
      Asm[(k0+1)*64+pos] = pa[j].y;
      Asm[(k0+2)*64+pos] = pa[j].z;
      Asm[(k0+3)*64+pos] = pa[j].w;
      int oc = f & 63, kq = f >> 6;
      Bsm[(kq*4+0)*64+oc] = pb[j].x;
      Bsm[(kq*4+1)*64+oc] = pb[j].y;
      Bsm[(kq*4+2)*64+oc] = pb[j].z;
      Bsm[(kq*4+3)*64+oc] = pb[j].w;
    }
    __syncthreads();
    if (t < 3) C2P_LOAD(t+1)
#pragma unroll 8
    for (int k = 0; k < 128; ++k) {
      float a0 = ap[k*64];
      float a1 = ap[k*64+32];
      float4 b0 = *(const float4*)&bp[k*64];
      float4 b1 = *(const float4*)&bp[k*64+4];
      acc0[0] += a0*b0.x; acc0[1] += a0*b0.y; acc0[2] += a0*b0.z; acc0[3] += a0*b0.w;
      acc0[4] += a0*b1.x; acc0[5] += a0*b1.y; acc0[6] += a0*b1.z; acc0[7] += a0*b1.w;
      acc1[0] += a1*b0.x; acc1[1] += a1*b0.y; acc1[2] += a1*b0.z; acc1[3] += a1*b0.w;
      acc1[4] += a1*b1.x; acc1[5] += a1*b1.y; acc1[6] += a1*b1.z; acc1[7] += a1*b1.w;
    }
  }
  const int ocb = ocg*64 + wv*16 + og*8;
  float* o0 = pd + (size_t)kc*1048576 + ((size_t)b*128 + ocb)*1024 + (pg*2)*32 + ox;
  float* o1 = o0 + 32;
#pragma unroll
  for (int j = 0; j < 8; ++j) {
    o0[(size_t)j*1024] = acc0[j];
    o1[(size_t)j*1024] = acc1[j];
  }
}

// ---------------- conv2 partial reduce: h = bias + p0 + p1 ----------------
__global__ __launch_bounds__(256) void k_c2red(const float* __restrict__ pd,
    const float* __restrict__ bias, float* __restrict__ h) {
  int i4 = blockIdx.x*256 + threadIdx.x;
  int oc = (i4 >> 8) & 127;
  float bv = bias[oc];
  const float4 p0 = ((const float4*)pd)[i4];
  const float4 p1 = ((const float4*)pd)[i4 + 262144];
  float4 r;
  r.x = bv + p0.x + p1.x; r.y = bv + p0.y + p1.y;
  r.z = bv + p0.z + p1.z; r.w = bv + p0.w + p1.w;
  ((float4*)h)[i4] = r;
}

// ---------------- res 3x3 as implicit GEMM over k=ic*9, kc-split x4 ----------------
// grid (kc4, yp16, b8) = 512 blocks; tile 64pos(2 rows) x 64oc; t-loop 4 x (8ic=72k).
// A[72][64] im2col staged from relu(h) (wave-scalar index math); B[72][64] weights.
__global__ __launch_bounds__(256) void k_res3(const float* __restrict__ h,
    const float* __restrict__ w, float* __restrict__ pd3) {
  __shared__ float A[72*64];
  __shared__ float B[72*64];
  const int b = blockIdx.z, yp = blockIdx.y, kc = blockIdx.x;
  const int tid = threadIdx.x, lane = tid & 63;
  const int wv = __builtin_amdgcn_readfirstlane(tid >> 6);
  const int col = lane & 31, og = lane >> 5;
  const int prow = lane >> 5;                    // staging row-part of pos
  const float* hb = h + (size_t)b*131072;
  const int row0 = yp*2;
  float acc0[8] = {0,0,0,0,0,0,0,0};
  float acc1[8] = {0,0,0,0,0,0,0,0};
  for (int tt = 0; tt < 4; ++tt) {
    const int ic0 = kc*32 + tt*8;
    __syncthreads();
#pragma unroll
    for (int j = 0; j < 18; ++j) {               // A: 72k x 64pos
      int k_rel = wv + j*4;                      // wave-scalar
      int ic_r = k_rel / 9;
      int tap = k_rel - ic_r*9;
      int dy = tap / 3, dx = tap - dy*3;
      int py = row0 + prow + dy - 1;
      int px = col + dx - 1;
      float v = 0.f;
      if (((unsigned)py < 32u) && ((unsigned)px < 32u))
        v = fmaxf(hb[(size_t)(ic0+ic_r)*1024 + py*32 + px], 0.f);
      A[k_rel*64 + lane] = v;
    }
#pragma unroll
    for (int j = 0; j < 5; ++j) {                // B: w[oc][ic0..+8][9] -> B[k][oc]
      int fi = tid + j*256;                      // 1152 float4s
      if (fi < 1152) {
        int oc = fi / 18, r = fi - oc*18;
        float4 v = *(const float4*)(w + (size_t)oc*1152 + ic0*9 + r*4);
        int kb = r*4;
        B[(kb+0)*64 + oc] = v.x;
        B[(kb+1)*64 + oc] = v.y;
        B[(kb+2)*64 + oc] = v.z;
        B[(kb+3)*64 + oc] = v.w;
      }
    }
    __syncthreads();
    const float* ap = A + col;
    const float* bp = B + wv*16 + og*8;
#pragma unroll 8
    for (int k = 0; k < 72; ++k) {
      float a0 = ap[k*64];
      float a1 = ap[k*64 + 32];
      float4 b0 = *(const float4*)(bp + k*64);
      float4 b1 = *(const float4*)(bp + k*64 + 4);
      acc0[0] += a0*b0.x; acc0[1] += a0*b0.y; acc0[2] += a0*b0.z; acc0[3] += a0*b0.w;
      acc0[4] += a0*b1.x; acc0[5] += a0*b1.y; acc0[6] += a0*b1.z; acc0[7] += a0*b1.w;
      acc1[0] += a1*b0.x; acc1[1] += a1*b0.y; acc1[2] += a1*b0.z; acc1[3] += a1*b0.w;
      acc1[4] += a1*b1.x; acc1[5] += a1*b1.y; acc1[6] += a1*b1.z; acc1[7] += a1*b1.w;
    }
  }
  const int ocb = wv*16 + og*8;
  float* o0 = pd3 + (size_t)kc*524288 + ((size_t)b*64 + ocb)*1024 + row0*32 + col;
#pragma unroll
  for (int j = 0; j < 8; ++j) {
    o0[(size_t)j*1024]      = acc0[j];
    o0[(size_t)j*1024 + 32] = acc1[j];
  }
}

// ---------------- res3 partial reduce: r1 = p0+p1+p2+p3 ----------------
__global__ __launch_bounds__(256) void k_r3red(const float* __restrict__ pd3,
    float* __restrict__ r1) {
  int i4 = blockIdx.x*256 + threadIdx.x;         // 131072 float4s
  float4 a = ((const float4*)pd3)[i4];
  float4 b = ((const float4*)pd3)[i4 + 131072];
  float4 c = ((const float4*)pd3)[i4 + 262144];
  float4 d = ((const float4*)pd3)[i4 + 393216];
  float4 r;
  r.x = ((a.x + b.x) + c.x) + d.x;
  r.y = ((a.y + b.y) + c.y) + d.y;
  r.z = ((a.z + b.z) + c.z) + d.z;
  r.w = ((a.w + b.w) + c.w) + d.w;
  ((float4*)r1)[i4] = r;
}

// ---------------- res 1x1: h += w2 @ relu(r1), 64->128 ----------------
// grid (pg=32, og=16); block = 256 pos x 8 oc; weights in LDS broadcast
__global__ __launch_bounds__(256) void k_res1(const float* __restrict__ r1,
    const float* __restrict__ w, float* __restrict__ h) {
  __shared__ float B[64*8];
  const int og = blockIdx.y;
  const int tid = threadIdx.x;
#pragma unroll
  for (int j = 0; j < 2; ++j) {
    int f = tid + j*256;                         // 512 floats
    int ocj = f >> 6, ic = f & 63;
    B[ic*8 + ocj] = w[(size_t)(og*8 + ocj)*64 + ic];
  }
  __syncthreads();
  const int p = blockIdx.x*256 + tid;
  const int b = p >> 10, rem = p & 1023;
  const float* rb = r1 + (size_t)b*65536 + rem;
  float acc[8] = {0,0,0,0,0,0,0,0};
  for (int ic = 0; ic < 64; ++ic) {
    float rv = fmaxf(rb[(size_t)ic*1024], 0.f);
    float4 w0 = *(const float4*)&B[ic*8];
    float4 w1 = *(const float4*)&B[ic*8 + 4];
    acc[0] += w0.x*rv; acc[1] += w0.y*rv; acc[2] += w0.z*rv; acc[3] += w0.w*rv;
    acc[4] += w1.x*rv; acc[5] += w1.y*rv; acc[6] += w1.z*rv; acc[7] += w1.w*rv;
  }
  float* hb = h + ((size_t)b*128 + og*8)*1024 + rem;
#pragma unroll
  for (int j = 0; j < 8; ++j) hb[(size_t)j*1024] += acc[j];
}

// ---------------- preq: z_e = pw @ relu(h) + pb, 128->64 ----------------
// grid (pg=32, eg=16); block = 256 pos x 4 e; weights in LDS broadcast
__global__ __launch_bounds__(256) void k_preq(const float* __restrict__ h,
    const float* __restrict__ w, const float* __restrict__ bias,
    float* __restrict__ ze) {
  __shared__ float B[128*4];
  const int eg = blockIdx.y;
  const int tid = threadIdx.x;
#pragma unroll
  for (int j = 0; j < 2; ++j) {
    int f = tid + j*256;                         // 512 floats
    int ej = f >> 7, ic = f & 127;
    B[ic*4 + ej] = w[(size_t)(eg*4 + ej)*128 + ic];
  }
  __syncthreads();
  const int p = blockIdx.x*256 + tid;
  const int b = p >> 10, rem = p & 1023;
  const float* hb = h + (size_t)b*131072 + rem;
  float acc[4] = {0,0,0,0};
  for (int ic = 0; ic < 128; ++ic) {
    float hv = fmaxf(hb[(size_t)ic*1024], 0.f);
    float4 wv4 = *(const float4*)&B[ic*4];
    acc[0] += wv4.x*hv; acc[1] += wv4.y*hv; acc[2] += wv4.z*hv; acc[3] += wv4.w*hv;
  }
#pragma unroll
  for (int j = 0; j < 4; ++j)
    ze[((size_t)b*64 + eg*4+j)*1024 + rem] = acc[j] + bias[eg*4+j];
}

// ---------------- e2[e] = ||emb_e||^2 ----------------
__global__ __launch_bounds__(256) void k_e2(const float* __restrict__ emb,
                                            float* __restrict__ e2) {
  int e = blockIdx.x*256 + threadIdx.x;
  const float* er = emb + (size_t)e*64;
  float s = 0.f;
#pragma unroll
  for (int i = 0; i < 16; ++i) {
    float4 v = *(const float4*)(er + i*4);
    s += v.x*v.x + v.y*v.y + v.z*v.z + v.w*v.w;
  }
  e2[e] = s;
}

// ---------------- VQ distances + per-strip argmin ----------------
__global__ __launch_bounds__(256) void k_vq(const float* __restrict__ ze,
    const float* __restrict__ emb, const float* __restrict__ e2,
    float* __restrict__ part_d, int* __restrict__ part_i) {
  const int bid = blockIdx.x;
  const int sg = bid & 15, pg = bid >> 4;
  const int tid = threadIdx.x, lane = tid & 63;
  const int wv = __builtin_amdgcn_readfirstlane(tid >> 6);
  const int s = sg*4 + wv;
  const int p = pg*64 + lane;
  const int b = p >> 10, rem = p & 1023;
  const float* zb = ze + (size_t)b*64*1024 + rem;
  float z[64];
#pragma unroll
  for (int i = 0; i < 64; ++i) z[i] = zb[(size_t)i*1024];
  float best = 3.4e38f; int bi = 0;
  const float* es = emb + (size_t)s*16*64;
  for (int j4 = 0; j4 < 16; j4 += 4) {
    float a0 = 0.f, a1 = 0.f, a2 = 0.f, a3 = 0.f;
#pragma unroll
    for (int i = 0; i < 64; ++i) {
      float zi = z[i];
      a0 += es[(j4+0)*64+i]*zi;
      a1 += es[(j4+1)*64+i]*zi;
      a2 += es[(j4+2)*64+i]*zi;
      a3 += es[(j4+3)*64+i]*zi;
    }
    float d0 = e2[s*16+j4+0] - 2.f*a0;
    float d1 = e2[s*16+j4+1] - 2.f*a1;
    float d2 = e2[s*16+j4+2] - 2.f*a2;
    float d3 = e2[s*16+j4+3] - 2.f*a3;
    if (d0 < best) { best = d0; bi = s*16+j4+0; }
    if (d1 < best) { best = d1; bi = s*16+j4+1; }
    if (d2 < best) { best = d2; bi = s*16+j4+2; }
    if (d3 < best) { best = d3; bi = s*16+j4+3; }
  }
  part_d[(size_t)s*NPOS + p] = best;
  part_i[(size_t)s*NPOS + p] = bi;
}

// ---------------- final argmin + z_q + loss partials + counts + idx ----------------
__global__ __launch_bounds__(256) void k_reduce(const float* __restrict__ part_d,
    const int* __restrict__ part_i, const float* __restrict__ emb,
    const float* __restrict__ ze, float* __restrict__ out,
    int* __restrict__ counts, float* __restrict__ sse) {
  const int p = blockIdx.x*256 + threadIdx.x;
  float best = 3.4e38f; int id = 0;
  for (int s = 0; s < 64; ++s) {
    float d = part_d[(size_t)s*NPOS + p];
    int   i = part_i[(size_t)s*NPOS + p];
    if (d < best) { best = d; id = i; }
  }
  out[IDX_OFF + p] = (float)id;
  atomicAdd(&counts[id], 1);
  const int b = p >> 10, rem = p & 1023;
  const float* zb = ze + (size_t)b*64*1024 + rem;
  float* qo = out + ZQ_OFF + (size_t)b*64*1024 + rem;
  const float* er = emb + (size_t)id*64;
  float local = 0.f;
#pragma unroll
  for (int e4 = 0; e4 < 16; ++e4) {
    float4 q = *(const float4*)(er + e4*4);
    float z0 = zb[(size_t)(e4*4+0)*1024];
    float z1 = zb[(size_t)(e4*4+1)*1024];
    float z2 = zb[(size_t)(e4*4+2)*1024];
    float z3 = zb[(size_t)(e4*4+3)*1024];
    qo[(size_t)(e4*4+0)*1024] = q.x;
    qo[(size_t)(e4*4+1)*1024] = q.y;
    qo[(size_t)(e4*4+2)*1024] = q.z;
    qo[(size_t)(e4*4+3)*1024] = q.w;
    float d0 = q.x - z0, d1 = q.y - z1, d2 = q.z - z2, d3 = q.w - z3;
    local += d0*d0 + d1*d1 + d2*d2 + d3*d3;
  }
  for (int off = 32; off; off >>= 1) local += __shfl_down(local, off);
  if ((threadIdx.x & 63) == 0) atomicAdd(sse, local);
}

// ---------------- scalars: loss & perplexity ----------------
__global__ __launch_bounds__(256) void k_final(const int* __restrict__ counts,
    const float* __restrict__ sse, float* __restrict__ out) {
  __shared__ float red[4];
  float part = 0.f;
  for (int e = threadIdx.x; e < 1024; e += 256) {
    float pm = (float)counts[e] * (1.f/8192.f);
    part += pm * logf(pm + 1e-10f);
  }
  for (int off = 32; off; off >>= 1) part += __shfl_down(part, off);
  if ((threadIdx.x & 63) == 0) red[threadIdx.x >> 6] = part;
  __syncthreads();
  if (threadIdx.x == 0) {
    float t = red[0] + red[1] + red[2] + red[3];
    out[PPL_OFF] = expf(-t);
    out[0] = 1.25f * sse[0] * (1.f/524288.f);
  }
}

// ---------------- launcher ----------------
extern "C" void kernel_launch(void* const* d_in, const int* in_sizes, int n_in,
                              void* d_out, int out_size, void* d_ws, size_t ws_size,
                              hipStream_t stream) {
  (void)in_sizes; (void)n_in; (void)out_size; (void)ws_size;
  const float* x   = (const float*)d_in[0];
  const float* w1  = (const float*)d_in[1];
  const float* b1  = (const float*)d_in[2];
  const float* w2  = (const float*)d_in[3];
  const float* b2  = (const float*)d_in[4];
  const float* rw1 = (const float*)d_in[5];
  const float* rw2 = (const float*)d_in[6];
  const float* pw  = (const float*)d_in[7];
  const float* pb  = (const float*)d_in[8];
  const float* emb = (const float*)d_in[9];
  float* out = (float*)d_out;
  char* ws = (char*)d_ws;
  // layout (total 46,145,540 B, same footprint as passing rounds):
  // [0,32MB)  h1 (conv1->conv2p), then REUSED as pd3 [0,8MB) (res3->r3red)
  float* h1     = (float*)(ws);
  float* pd3    = (float*)(ws);                    // res3 partials, h1 dead by then
  float* c2pd   = (float*)(ws + 33554432);         // conv2 partials [32,40MB)
  float* r1     = (float*)(ws + 33554432);         // reuse after c2red [32,34MB)
  float* ze     = (float*)(ws + 35651584);         // [34,36MB)
  float* pd     = (float*)(ws + 37748736);         // VQ partial dist [36,38MB)
  int*   pi     = (int*)  (ws + 39845888);         // VQ partial idx  [38,40MB)
  float* h      = (float*)(ws + 41943040);         // [40,44MB)
  float* e2     = (float*)(ws + 46137344);
  int*   counts = (int*)  (ws + 46141440);
  float* sse    = (float*)(ws + 46145536);

  hipMemsetAsync(counts, 0, 1024*4 + 4, stream);
  k_conv1<<<dim3(2,128,8), 256, 0, stream>>>(x, w1, b1, h1);
  k_conv2p<<<dim3(4,16,8), 256, 0, stream>>>(h1, w2, c2pd);
  k_c2red<<<1024, 256, 0, stream>>>(c2pd, b2, h);
  for (int it = 0; it < 2; ++it) {
    k_res3<<<dim3(4,16,8), 256, 0, stream>>>(h, rw1, pd3);
    k_r3red<<<512, 256, 0, stream>>>(pd3, r1);
    k_res1<<<dim3(32,16), 256, 0, stream>>>(r1, rw2, h);
  }
  k_preq<<<dim3(32,16), 256, 0, stream>>>(h, pw, pb, ze);
  k_e2<<<4, 256, 0, stream>>>(emb, e2);
  k_vq<<<2048, 256, 0, stream>>>(ze, emb, e2, pd, pi);
  k_reduce<<<32, 256, 0, stream>>>(pd, pi, emb, ze, out, counts, sse);
  k_final<<<1, 256, 0, stream>>>(counts, sse, out);
  hipMemcpyAsync(out + EMB_OFF, emb, 65536*4, hipMemcpyDeviceToDevice, stream);
}

// Round 8
// 302.003 us; speedup vs baseline: 2.0108x; 1.1308x over previous
//
#include <hip/hip_runtime.h>

// ---------------- problem constants ----------------
// x [8,3,512,512] -> conv1(4x4 s4)+relu -> h1 [8,64,128,128]    (GEMM, LDS A+B)
// -> conv2(4x4 s4)+bias -> h [8,128,32,32]                      (GEMM, K-split x2)
// -> 2x { r = conv3x3(relu(h)) [8,64,32,32]; h += conv1x1(relu(r)) }  (GEMM, kc x8)
// -> relu -> preq 1x1 + bias -> z_e [8,64,32,32]
// -> VQ against emb [1024,64]; outputs: loss, z_q [8,64,32,32], ppl, emb, idx
#define NPOS 8192
#define ZQ_OFF   1
#define PPL_OFF  524289
#define EMB_OFF  524290
#define IDX_OFF  589826

// ---------------- conv1 as implicit GEMM: K=48, tile 64pos x 64oc ----------------
__global__ __launch_bounds__(256) void k_conv1(const float* __restrict__ x,
    const float* __restrict__ w, const float* __restrict__ bias,
    float* __restrict__ out) {
  __shared__ float A[48*64];
  __shared__ float B[48*64];
  const int b = blockIdx.z, oy = blockIdx.y, xh = blockIdx.x;
  const int tid = threadIdx.x, lane = tid & 63;
  const int wv = __builtin_amdgcn_readfirstlane(tid >> 6);
  const int col = lane & 31, og = lane >> 5;
  const float* xb = x + (size_t)b*786432 + (size_t)(oy*4)*512 + xh*256;
#pragma unroll
  for (int j = 0; j < 3; ++j) {                  // A: [k=c*16+iy*4+ix][pos]
    int f = tid + j*256;                         // 768 float4s
    int c = f >> 8, iy = (f >> 6) & 3, x4 = f & 63;
    float4 v = *(const float4*)(xb + (size_t)c*262144 + (size_t)iy*512 + x4*4);
    int k0 = c*16 + iy*4;
    A[(k0+0)*64 + x4] = v.x;
    A[(k0+1)*64 + x4] = v.y;
    A[(k0+2)*64 + x4] = v.z;
    A[(k0+3)*64 + x4] = v.w;
  }
#pragma unroll
  for (int j = 0; j < 3; ++j) {                  // B: w[oc][48] -> B[k][oc]
    int fi = tid + j*256;
    float4 v = ((const float4*)w)[fi];
    int base = fi*4;
#pragma unroll
    for (int e = 0; e < 4; ++e) {
      int f = base + e;
      int oc = f / 48, k = f - oc*48;
      B[k*64 + oc] = (&v.x)[e];
    }
  }
  __syncthreads();
  const int ocb = wv*16 + og*8;
  float acc0[8], acc1[8];
#pragma unroll
  for (int j = 0; j < 8; ++j) { acc0[j] = bias[ocb+j]; acc1[j] = acc0[j]; }
  const float* ap = A + col;
  const float* bp = B + ocb;
#pragma unroll 8
  for (int k = 0; k < 48; ++k) {
    float a0 = ap[k*64];
    float a1 = ap[k*64 + 32];
    float4 b0 = *(const float4*)(bp + k*64);
    float4 b1 = *(const float4*)(bp + k*64 + 4);
    acc0[0] += a0*b0.x; acc0[1] += a0*b0.y; acc0[2] += a0*b0.z; acc0[3] += a0*b0.w;
    acc0[4] += a0*b1.x; acc0[5] += a0*b1.y; acc0[6] += a0*b1.z; acc0[7] += a0*b1.w;
    acc1[0] += a1*b0.x; acc1[1] += a1*b0.y; acc1[2] += a1*b0.z; acc1[3] += a1*b0.w;
    acc1[4] += a1*b1.x; acc1[5] += a1*b1.y; acc1[6] += a1*b1.z; acc1[7] += a1*b1.w;
  }
  float* ob = out + ((size_t)(b*64 + ocb))*16384 + oy*128 + xh*64 + col;
#pragma unroll
  for (int j = 0; j < 8; ++j) {
    ob[(size_t)j*16384]      = fmaxf(acc0[j], 0.f);
    ob[(size_t)j*16384 + 32] = fmaxf(acc1[j], 0.f);
  }
}

// ---------------- conv2 (implicit GEMM, K-split x2) — unchanged ----------------
__global__ __launch_bounds__(256) void k_conv2p(const float* __restrict__ h1,
    const float* __restrict__ w, float* __restrict__ pd) {
  __shared__ float Asm[128*64];
  __shared__ float Bsm[128*64];
  const int b = blockIdx.z, pg = blockIdx.y;
  const int kc = blockIdx.x & 1, ocg = blockIdx.x >> 1;
  const int tid = threadIdx.x;
  const int lane = tid & 63;
  const int wv = __builtin_amdgcn_readfirstlane(tid >> 6);
  const int ox = lane & 31, og = lane >> 5;
  float4 pa[8], pb[8];
  const float* srcA = h1 + ((size_t)(b*64 + kc*32)) * 16384 + (size_t)(pg*8) * 128;
  const float* srcB = w + (size_t)(ocg*64) * 1024 + kc*512;
#define C2P_LOAD(t) { \
    _Pragma("unroll") \
    for (int j = 0; j < 8; ++j) { \
      int f = tid + j*256; \
      int x4 = f & 31, r = (f>>5) & 7, i = f >> 8; \
      pa[j] = *(const float4*)(srcA + (size_t)((t)*8+i)*16384 + r*128 + x4*4); \
      int oc = f & 63, kq = f >> 6; \
      pb[j] = *(const float4*)(srcB + (size_t)oc*1024 + (t)*128 + kq*4); \
    } }
  C2P_LOAD(0)
  float acc0[8] = {0,0,0,0,0,0,0,0};
  float acc1[8] = {0,0,0,0,0,0,0,0};
  const float* ap = &Asm[ox];
  const float* bp = &Bsm[wv*16 + og*8];
  for (int t = 0; t < 4; ++t) {
    __syncthreads();
#pragma unroll
    for (int j = 0; j < 8; ++j) {
      int f = tid + j*256;
      int x4 = f & 31, r = (f>>5) & 7, i = f >> 8;
      int k0 = i*16 + (r&3)*4, pos = (r>>2)*32 + x4;
      Asm[(k0+0)*64+pos] = pa[j].x;
      Asm[(k0+1)*64+pos] = pa[j].y;
      Asm[(k0+2)*64+pos] = pa[j].z;
      Asm[(k0+3)*64+pos] = pa[j].w;
      int oc = f & 63, kq = f >> 6;
      Bsm[(kq*4+0)*64+oc] = pb[j].x;
      Bsm[(kq*4+1)*64+oc] = pb[j].y;
      Bsm[(kq*4+2)*64+oc] = pb[j].z;
      Bsm[(kq*4+3)*64+oc] = pb[j].w;
    }
    __syncthreads();
    if (t < 3) C2P_LOAD(t+1)
#pragma unroll 8
    for (int k = 0; k < 128; ++k) {
      float a0 = ap[k*64];
      float a1 = ap[k*64+32];
      float4 b0 = *(const float4*)&bp[k*64];
      float4 b1 = *(const float4*)&bp[k*64+4];
      acc0[0] += a0*b0.x; acc0[1] += a0*b0.y; acc0[2] += a0*b0.z; acc0[3] += a0*b0.w;
      acc0[4] += a0*b1.x; acc0[5] += a0*b1.y; acc0[6] += a0*b1.z; acc0[7] += a0*b1.w;
      acc1[0] += a1*b0.x; acc1[1] += a1*b0.y; acc1[2] += a1*b0.z; acc1[3] += a1*b0.w;
      acc1[4] += a1*b1.x; acc1[5] += a1*b1.y; acc1[6] += a1*b1.z; acc1[7] += a1*b1.w;
    }
  }
  const int ocb = ocg*64 + wv*16 + og*8;
  float* o0 = pd + (size_t)kc*1048576 + ((size_t)b*128 + ocb)*1024 + (pg*2)*32 + ox;
  float* o1 = o0 + 32;
#pragma unroll
  for (int j = 0; j < 8; ++j) {
    o0[(size_t)j*1024] = acc0[j];
    o1[(size_t)j*1024] = acc1[j];
  }
}

// ---------------- conv2 partial reduce: h = bias + p0 + p1 ----------------
__global__ __launch_bounds__(256) void k_c2red(const float* __restrict__ pd,
    const float* __restrict__ bias, float* __restrict__ h) {
  int i4 = blockIdx.x*256 + threadIdx.x;
  int oc = (i4 >> 8) & 127;
  float bv = bias[oc];
  const float4 p0 = ((const float4*)pd)[i4];
  const float4 p1 = ((const float4*)pd)[i4 + 262144];
  float4 r;
  r.x = bv + p0.x + p1.x; r.y = bv + p0.y + p1.y;
  r.z = bv + p0.z + p1.z; r.w = bv + p0.w + p1.w;
  ((float4*)h)[i4] = r;
}

// ---------------- res 3x3 as implicit GEMM, kc-split x8, prefetched ----------------
// grid (kc8, yp16, b8) = 1024 blocks (4/CU); tile 64pos(2 rows) x 64oc; 2 tt x 8 ic.
// A[72][64] im2col (reg-prefetched); B[72][64] weights, oc=lane staging -> no conflicts.
__global__ __launch_bounds__(256) void k_res3(const float* __restrict__ h,
    const float* __restrict__ w, float* __restrict__ pd3) {
  __shared__ float A[72*64];
  __shared__ float B[72*64];
  const int b = blockIdx.z, yp = blockIdx.y, kc = blockIdx.x;   // kc 0..7
  const int tid = threadIdx.x, lane = tid & 63;
  const int wv = __builtin_amdgcn_readfirstlane(tid >> 6);
  const int col = lane & 31, og = lane >> 5;
  const int prow = lane >> 5;
  const float* hb = h + (size_t)b*131072;
  const int row0 = yp*2;
  float prA[18];
  float4 prB[5];
#define R3_LOADA(t) { \
    _Pragma("unroll") \
    for (int j = 0; j < 18; ++j) { \
      int k_rel = wv + j*4; \
      int ic_r = k_rel/9, tap = k_rel - ic_r*9; \
      int dy = tap/3, dx = tap - dy*3; \
      int py = row0 + prow + dy - 1, px = col + dx - 1; \
      float v = 0.f; \
      if (((unsigned)py < 32u) && ((unsigned)px < 32u)) \
        v = fmaxf(hb[(size_t)(kc*16 + (t)*8 + ic_r)*1024 + py*32 + px], 0.f); \
      prA[j] = v; \
    } }
#define R3_LOADB(t) { \
    _Pragma("unroll") \
    for (int j = 0; j < 5; ++j) { \
      int rr = wv + j*4; \
      if (rr < 18) \
        prB[j] = *(const float4*)(w + (size_t)lane*1152 + (kc*16 + (t)*8)*9 + rr*4); \
    } }
  R3_LOADA(0) R3_LOADB(0)
  float acc0[8] = {0,0,0,0,0,0,0,0};
  float acc1[8] = {0,0,0,0,0,0,0,0};
  for (int tt = 0; tt < 2; ++tt) {
    __syncthreads();
#pragma unroll
    for (int j = 0; j < 18; ++j) {               // A store: banks = lane%32, 2-way free
      int k_rel = wv + j*4;
      A[k_rel*64 + lane] = prA[j];
    }
#pragma unroll
    for (int j = 0; j < 5; ++j) {                // B store: oc = lane -> conflict-free
      int rr = wv + j*4;
      if (rr < 18) {
        B[(rr*4+0)*64 + lane] = prB[j].x;
        B[(rr*4+1)*64 + lane] = prB[j].y;
        B[(rr*4+2)*64 + lane] = prB[j].z;
        B[(rr*4+3)*64 + lane] = prB[j].w;
      }
    }
    __syncthreads();
    if (tt == 0) { R3_LOADA(1) R3_LOADB(1) }
    const float* ap = A + col;
    const float* bp = B + wv*16 + og*8;
#pragma unroll 8
    for (int k = 0; k < 72; ++k) {
      float a0 = ap[k*64];
      float a1 = ap[k*64 + 32];
      float4 b0 = *(const float4*)(bp + k*64);
      float4 b1 = *(const float4*)(bp + k*64 + 4);
      acc0[0] += a0*b0.x; acc0[1] += a0*b0.y; acc0[2] += a0*b0.z; acc0[3] += a0*b0.w;
      acc0[4] += a0*b1.x; acc0[5] += a0*b1.y; acc0[6] += a0*b1.z; acc0[7] += a0*b1.w;
      acc1[0] += a1*b0.x; acc1[1] += a1*b0.y; acc1[2] += a1*b0.z; acc1[3] += a1*b0.w;
      acc1[4] += a1*b1.x; acc1[5] += a1*b1.y; acc1[6] += a1*b1.z; acc1[7] += a1*b1.w;
    }
  }
  const int ocb = wv*16 + og*8;
  float* o0 = pd3 + (size_t)kc*524288 + ((size_t)b*64 + ocb)*1024 + row0*32 + col;
#pragma unroll
  for (int j = 0; j < 8; ++j) {
    o0[(size_t)j*1024]      = acc0[j];
    o0[(size_t)j*1024 + 32] = acc1[j];
  }
}

// ---------------- res3 partial reduce: r1 = sum of 8 kc-partials ----------------
__global__ __launch_bounds__(256) void k_r3red(const float* __restrict__ pd3,
    float* __restrict__ r1) {
  int i4 = blockIdx.x*256 + threadIdx.x;         // 131072 float4s
  float4 s = ((const float4*)pd3)[i4];
#pragma unroll
  for (int c = 1; c < 8; ++c) {
    float4 p = ((const float4*)pd3)[i4 + c*131072];
    s.x += p.x; s.y += p.y; s.z += p.z; s.w += p.w;
  }
  ((float4*)r1)[i4] = s;
}

// ---------------- res 1x1: h += w2 @ relu(r1), 64->128 ----------------
__global__ __launch_bounds__(256) void k_res1(const float* __restrict__ r1,
    const float* __restrict__ w, float* __restrict__ h) {
  __shared__ float B[64*8];
  const int og = blockIdx.y;
  const int tid = threadIdx.x;
#pragma unroll
  for (int j = 0; j < 2; ++j) {
    int f = tid + j*256;                         // 512 floats
    int ocj = f >> 6, ic = f & 63;
    B[ic*8 + ocj] = w[(size_t)(og*8 + ocj)*64 + ic];
  }
  __syncthreads();
  const int p = blockIdx.x*256 + tid;
  const int b = p >> 10, rem = p & 1023;
  const float* rb = r1 + (size_t)b*65536 + rem;
  float acc[8] = {0,0,0,0,0,0,0,0};
  for (int ic = 0; ic < 64; ++ic) {
    float rv = fmaxf(rb[(size_t)ic*1024], 0.f);
    float4 w0 = *(const float4*)&B[ic*8];
    float4 w1 = *(const float4*)&B[ic*8 + 4];
    acc[0] += w0.x*rv; acc[1] += w0.y*rv; acc[2] += w0.z*rv; acc[3] += w0.w*rv;
    acc[4] += w1.x*rv; acc[5] += w1.y*rv; acc[6] += w1.z*rv; acc[7] += w1.w*rv;
  }
  float* hb = h + ((size_t)b*128 + og*8)*1024 + rem;
#pragma unroll
  for (int j = 0; j < 8; ++j) hb[(size_t)j*1024] += acc[j];
}

// ---------------- preq: z_e = pw @ relu(h) + pb, 128->64 ----------------
__global__ __launch_bounds__(256) void k_preq(const float* __restrict__ h,
    const float* __restrict__ w, const float* __restrict__ bias,
    float* __restrict__ ze) {
  __shared__ float B[128*4];
  const int eg = blockIdx.y;
  const int tid = threadIdx.x;
#pragma unroll
  for (int j = 0; j < 2; ++j) {
    int f = tid + j*256;                         // 512 floats
    int ej = f >> 7, ic = f & 127;
    B[ic*4 + ej] = w[(size_t)(eg*4 + ej)*128 + ic];
  }
  __syncthreads();
  const int p = blockIdx.x*256 + tid;
  const int b = p >> 10, rem = p & 1023;
  const float* hb = h + (size_t)b*131072 + rem;
  float acc[4] = {0,0,0,0};
  for (int ic = 0; ic < 128; ++ic) {
    float hv = fmaxf(hb[(size_t)ic*1024], 0.f);
    float4 wv4 = *(const float4*)&B[ic*4];
    acc[0] += wv4.x*hv; acc[1] += wv4.y*hv; acc[2] += wv4.z*hv; acc[3] += wv4.w*hv;
  }
#pragma unroll
  for (int j = 0; j < 4; ++j)
    ze[((size_t)b*64 + eg*4+j)*1024 + rem] = acc[j] + bias[eg*4+j];
}

// ---------------- e2[e] = ||emb_e||^2 ----------------
__global__ __launch_bounds__(256) void k_e2(const float* __restrict__ emb,
                                            float* __restrict__ e2) {
  int e = blockIdx.x*256 + threadIdx.x;
  const float* er = emb + (size_t)e*64;
  float s = 0.f;
#pragma unroll
  for (int i = 0; i < 16; ++i) {
    float4 v = *(const float4*)(er + i*4);
    s += v.x*v.x + v.y*v.y + v.z*v.z + v.w*v.w;
  }
  e2[e] = s;
}

// ---------------- VQ distances + per-strip argmin ----------------
__global__ __launch_bounds__(256) void k_vq(const float* __restrict__ ze,
    const float* __restrict__ emb, const float* __restrict__ e2,
    float* __restrict__ part_d, int* __restrict__ part_i) {
  const int bid = blockIdx.x;
  const int sg = bid & 15, pg = bid >> 4;
  const int tid = threadIdx.x, lane = tid & 63;
  const int wv = __builtin_amdgcn_readfirstlane(tid >> 6);
  const int s = sg*4 + wv;
  const int p = pg*64 + lane;
  const int b = p >> 10, rem = p & 1023;
  const float* zb = ze + (size_t)b*64*1024 + rem;
  float z[64];
#pragma unroll
  for (int i = 0; i < 64; ++i) z[i] = zb[(size_t)i*1024];
  float best = 3.4e38f; int bi = 0;
  const float* es = emb + (size_t)s*16*64;
  for (int j4 = 0; j4 < 16; j4 += 4) {
    float a0 = 0.f, a1 = 0.f, a2 = 0.f, a3 = 0.f;
#pragma unroll
    for (int i = 0; i < 64; ++i) {
      float zi = z[i];
      a0 += es[(j4+0)*64+i]*zi;
      a1 += es[(j4+1)*64+i]*zi;
      a2 += es[(j4+2)*64+i]*zi;
      a3 += es[(j4+3)*64+i]*zi;
    }
    float d0 = e2[s*16+j4+0] - 2.f*a0;
    float d1 = e2[s*16+j4+1] - 2.f*a1;
    float d2 = e2[s*16+j4+2] - 2.f*a2;
    float d3 = e2[s*16+j4+3] - 2.f*a3;
    if (d0 < best) { best = d0; bi = s*16+j4+0; }
    if (d1 < best) { best = d1; bi = s*16+j4+1; }
    if (d2 < best) { best = d2; bi = s*16+j4+2; }
    if (d3 < best) { best = d3; bi = s*16+j4+3; }
  }
  part_d[(size_t)s*NPOS + p] = best;
  part_i[(size_t)s*NPOS + p] = bi;
}

// ---------------- final argmin + z_q + loss partials + counts + idx ----------------
__global__ __launch_bounds__(256) void k_reduce(const float* __restrict__ part_d,
    const int* __restrict__ part_i, const float* __restrict__ emb,
    const float* __restrict__ ze, float* __restrict__ out,
    int* __restrict__ counts, float* __restrict__ sse) {
  const int p = blockIdx.x*256 + threadIdx.x;
  float best = 3.4e38f; int id = 0;
  for (int s = 0; s < 64; ++s) {
    float d = part_d[(size_t)s*NPOS + p];
    int   i = part_i[(size_t)s*NPOS + p];
    if (d < best) { best = d; id = i; }
  }
  out[IDX_OFF + p] = (float)id;
  atomicAdd(&counts[id], 1);
  const int b = p >> 10, rem = p & 1023;
  const float* zb = ze + (size_t)b*64*1024 + rem;
  float* qo = out + ZQ_OFF + (size_t)b*64*1024 + rem;
  const float* er = emb + (size_t)id*64;
  float local = 0.f;
#pragma unroll
  for (int e4 = 0; e4 < 16; ++e4) {
    float4 q = *(const float4*)(er + e4*4);
    float z0 = zb[(size_t)(e4*4+0)*1024];
    float z1 = zb[(size_t)(e4*4+1)*1024];
    float z2 = zb[(size_t)(e4*4+2)*1024];
    float z3 = zb[(size_t)(e4*4+3)*1024];
    qo[(size_t)(e4*4+0)*1024] = q.x;
    qo[(size_t)(e4*4+1)*1024] = q.y;
    qo[(size_t)(e4*4+2)*1024] = q.z;
    qo[(size_t)(e4*4+3)*1024] = q.w;
    float d0 = q.x - z0, d1 = q.y - z1, d2 = q.z - z2, d3 = q.w - z3;
    local += d0*d0 + d1*d1 + d2*d2 + d3*d3;
  }
  for (int off = 32; off; off >>= 1) local += __shfl_down(local, off);
  if ((threadIdx.x & 63) == 0) atomicAdd(sse, local);
}

// ---------------- scalars: loss & perplexity ----------------
__global__ __launch_bounds__(256) void k_final(const int* __restrict__ counts,
    const float* __restrict__ sse, float* __restrict__ out) {
  __shared__ float red[4];
  float part = 0.f;
  for (int e = threadIdx.x; e < 1024; e += 256) {
    float pm = (float)counts[e] * (1.f/8192.f);
    part += pm * logf(pm + 1e-10f);
  }
  for (int off = 32; off; off >>= 1) part += __shfl_down(part, off);
  if ((threadIdx.x & 63) == 0) red[threadIdx.x >> 6] = part;
  __syncthreads();
  if (threadIdx.x == 0) {
    float t = red[0] + red[1] + red[2] + red[3];
    out[PPL_OFF] = expf(-t);
    out[0] = 1.25f * sse[0] * (1.f/524288.f);
  }
}

// ---------------- launcher ----------------
extern "C" void kernel_launch(void* const* d_in, const int* in_sizes, int n_in,
                              void* d_out, int out_size, void* d_ws, size_t ws_size,
                              hipStream_t stream) {
  (void)in_sizes; (void)n_in; (void)out_size; (void)ws_size;
  const float* x   = (const float*)d_in[0];
  const float* w1  = (const float*)d_in[1];
  const float* b1  = (const float*)d_in[2];
  const float* w2  = (const float*)d_in[3];
  const float* b2  = (const float*)d_in[4];
  const float* rw1 = (const float*)d_in[5];
  const float* rw2 = (const float*)d_in[6];
  const float* pw  = (const float*)d_in[7];
  const float* pb  = (const float*)d_in[8];
  const float* emb = (const float*)d_in[9];
  float* out = (float*)d_out;
  char* ws = (char*)d_ws;
  // layout (total 46,145,540 B):
  // [0,32MB)  h1 (conv1->conv2p), then REUSED as pd3 [0,16MB) (res3->r3red)
  float* h1     = (float*)(ws);
  float* pd3    = (float*)(ws);                    // res3 partials (8x2MB), h1 dead
  float* c2pd   = (float*)(ws + 33554432);         // conv2 partials [32,40MB)
  float* r1     = (float*)(ws + 33554432);         // reuse after c2red [32,34MB)
  float* ze     = (float*)(ws + 35651584);         // [34,36MB)
  float* pd     = (float*)(ws + 37748736);         // VQ partial dist [36,38MB)
  int*   pi     = (int*)  (ws + 39845888);         // VQ partial idx  [38,40MB)
  float* h      = (float*)(ws + 41943040);         // [40,44MB)
  float* e2     = (float*)(ws + 46137344);
  int*   counts = (int*)  (ws + 46141440);
  float* sse    = (float*)(ws + 46145536);

  hipMemsetAsync(counts, 0, 1024*4 + 4, stream);
  k_conv1<<<dim3(2,128,8), 256, 0, stream>>>(x, w1, b1, h1);
  k_conv2p<<<dim3(4,16,8), 256, 0, stream>>>(h1, w2, c2pd);
  k_c2red<<<1024, 256, 0, stream>>>(c2pd, b2, h);
  for (int it = 0; it < 2; ++it) {
    k_res3<<<dim3(8,16,8), 256, 0, stream>>>(h, rw1, pd3);
    k_r3red<<<512, 256, 0, stream>>>(pd3, r1);
    k_res1<<<dim3(32,16), 256, 0, stream>>>(r1, rw2, h);
  }
  k_preq<<<dim3(32,16), 256, 0, stream>>>(h, pw, pb, ze);
  k_e2<<<4, 256, 0, stream>>>(emb, e2);
  k_vq<<<2048, 256, 0, stream>>>(ze, emb, e2, pd, pi);
  k_reduce<<<32, 256, 0, stream>>>(pd, pi, emb, ze, out, counts, sse);
  k_final<<<1, 256, 0, stream>>>(counts, sse, out);
  hipMemcpyAsync(out + EMB_OFF, emb, 65536*4, hipMemcpyDeviceToDevice, stream);
}

// Round 9
// 300.410 us; speedup vs baseline: 2.0215x; 1.0053x over previous
//
#include <hip/hip_runtime.h>

// ---------------- problem constants ----------------
// x [8,3,512,512] -> conv1(4x4 s4)+relu -> h1 [8,64,128,128]    (GEMM, LDS A+B)
// -> conv2(4x4 s4)+bias -> h [8,128,32,32]                      (GEMM, K-split x2)
// -> 2x { r = conv3x3(relu(h)) [8,64,32,32]; h += conv1x1(relu(r)) }  (GEMM, kc x8)
// -> relu -> preq 1x1 + bias -> z_e [8,64,32,32]
// -> VQ against emb [1024,64]; outputs: loss, z_q [8,64,32,32], ppl, emb, idx
#define NPOS 8192
#define ZQ_OFF   1
#define PPL_OFF  524289
#define EMB_OFF  524290
#define IDX_OFF  589826

// ---------------- conv1 as implicit GEMM: K=48, tile 64pos x 64oc ----------------
__global__ __launch_bounds__(256) void k_conv1(const float* __restrict__ x,
    const float* __restrict__ w, const float* __restrict__ bias,
    float* __restrict__ out) {
  __shared__ float A[48*64];
  __shared__ float B[48*64];
  const int b = blockIdx.z, oy = blockIdx.y, xh = blockIdx.x;
  const int tid = threadIdx.x, lane = tid & 63;
  const int wv = __builtin_amdgcn_readfirstlane(tid >> 6);
  const int col = lane & 31, og = lane >> 5;
  const float* xb = x + (size_t)b*786432 + (size_t)(oy*4)*512 + xh*256;
#pragma unroll
  for (int j = 0; j < 3; ++j) {                  // A: [k=c*16+iy*4+ix][pos]
    int f = tid + j*256;                         // 768 float4s
    int c = f >> 8, iy = (f >> 6) & 3, x4 = f & 63;
    float4 v = *(const float4*)(xb + (size_t)c*262144 + (size_t)iy*512 + x4*4);
    int k0 = c*16 + iy*4;
    A[(k0+0)*64 + x4] = v.x;
    A[(k0+1)*64 + x4] = v.y;
    A[(k0+2)*64 + x4] = v.z;
    A[(k0+3)*64 + x4] = v.w;
  }
#pragma unroll
  for (int j = 0; j < 3; ++j) {                  // B: w[oc][48] -> B[k][oc]
    int fi = tid + j*256;
    float4 v = ((const float4*)w)[fi];
    int base = fi*4;
#pragma unroll
    for (int e = 0; e < 4; ++e) {
      int f = base + e;
      int oc = f / 48, k = f - oc*48;
      B[k*64 + oc] = (&v.x)[e];
    }
  }
  __syncthreads();
  const int ocb = wv*16 + og*8;
  float acc0[8], acc1[8];
#pragma unroll
  for (int j = 0; j < 8; ++j) { acc0[j] = bias[ocb+j]; acc1[j] = acc0[j]; }
  const float* ap = A + col;
  const float* bp = B + ocb;
#pragma unroll 8
  for (int k = 0; k < 48; ++k) {
    float a0 = ap[k*64];
    float a1 = ap[k*64 + 32];
    float4 b0 = *(const float4*)(bp + k*64);
    float4 b1 = *(const float4*)(bp + k*64 + 4);
    acc0[0] += a0*b0.x; acc0[1] += a0*b0.y; acc0[2] += a0*b0.z; acc0[3] += a0*b0.w;
    acc0[4] += a0*b1.x; acc0[5] += a0*b1.y; acc0[6] += a0*b1.z; acc0[7] += a0*b1.w;
    acc1[0] += a1*b0.x; acc1[1] += a1*b0.y; acc1[2] += a1*b0.z; acc1[3] += a1*b0.w;
    acc1[4] += a1*b1.x; acc1[5] += a1*b1.y; acc1[6] += a1*b1.z; acc1[7] += a1*b1.w;
  }
  float* ob = out + ((size_t)(b*64 + ocb))*16384 + oy*128 + xh*64 + col;
#pragma unroll
  for (int j = 0; j < 8; ++j) {
    ob[(size_t)j*16384]      = fmaxf(acc0[j], 0.f);
    ob[(size_t)j*16384 + 32] = fmaxf(acc1[j], 0.f);
  }
}

// ---------------- conv2 (implicit GEMM, K-split x2, K-chunk 64) ----------------
// grid (x: kc2 | ocg2 = 4, y: pg16, z: b8) = 512 blocks; 256 thr = 4 waves.
// LDS: A [64k][64pos] 16KB + B [64k][64oc] 16KB = 32KB -> 4-5 blocks/CU.
// t-loop 8 x (4 ic = 64 k), register prefetch.
__global__ __launch_bounds__(256) void k_conv2p(const float* __restrict__ h1,
    const float* __restrict__ w, float* __restrict__ pd) {
  __shared__ float Asm[64*64];
  __shared__ float Bsm[64*64];
  const int b = blockIdx.z, pg = blockIdx.y;
  const int kc = blockIdx.x & 1, ocg = blockIdx.x >> 1;
  const int tid = threadIdx.x;
  const int lane = tid & 63;
  const int wv = __builtin_amdgcn_readfirstlane(tid >> 6);
  const int ox = lane & 31, og = lane >> 5;
  float4 pa[4], pb[4];
  const float* srcA = h1 + ((size_t)(b*64 + kc*32)) * 16384 + (size_t)(pg*8) * 128;
  const float* srcB = w + (size_t)(ocg*64) * 1024 + kc*512;
#define C2P_LOAD(t) { \
    _Pragma("unroll") \
    for (int j = 0; j < 4; ++j) { \
      int f = tid + j*256; \
      int x4 = f & 31, r = (f>>5) & 7, i = f >> 8; \
      pa[j] = *(const float4*)(srcA + (size_t)((t)*4+i)*16384 + r*128 + x4*4); \
      int oc = f & 63, kq = f >> 6; \
      pb[j] = *(const float4*)(srcB + (size_t)oc*1024 + (t)*64 + kq*4); \
    } }
  C2P_LOAD(0)
  float acc0[8] = {0,0,0,0,0,0,0,0};
  float acc1[8] = {0,0,0,0,0,0,0,0};
  const float* ap = &Asm[ox];
  const float* bp = &Bsm[wv*16 + og*8];
  for (int t = 0; t < 8; ++t) {
    __syncthreads();
#pragma unroll
    for (int j = 0; j < 4; ++j) {
      int f = tid + j*256;
      int x4 = f & 31, r = (f>>5) & 7, i = f >> 8;
      int k0 = i*16 + (r&3)*4, pos = (r>>2)*32 + x4;   // ky=r&3, oyL=r>>2, kx=delta
      Asm[(k0+0)*64+pos] = pa[j].x;
      Asm[(k0+1)*64+pos] = pa[j].y;
      Asm[(k0+2)*64+pos] = pa[j].z;
      Asm[(k0+3)*64+pos] = pa[j].w;
      int oc = f & 63, kq = f >> 6;
      Bsm[(kq*4+0)*64+oc] = pb[j].x;
      Bsm[(kq*4+1)*64+oc] = pb[j].y;
      Bsm[(kq*4+2)*64+oc] = pb[j].z;
      Bsm[(kq*4+3)*64+oc] = pb[j].w;
    }
    __syncthreads();
    if (t < 7) C2P_LOAD(t+1)
#pragma unroll 8
    for (int k = 0; k < 64; ++k) {
      float a0 = ap[k*64];
      float a1 = ap[k*64+32];
      float4 b0 = *(const float4*)&bp[k*64];
      float4 b1 = *(const float4*)&bp[k*64+4];
      acc0[0] += a0*b0.x; acc0[1] += a0*b0.y; acc0[2] += a0*b0.z; acc0[3] += a0*b0.w;
      acc0[4] += a0*b1.x; acc0[5] += a0*b1.y; acc0[6] += a0*b1.z; acc0[7] += a0*b1.w;
      acc1[0] += a1*b0.x; acc1[1] += a1*b0.y; acc1[2] += a1*b0.z; acc1[3] += a1*b0.w;
      acc1[4] += a1*b1.x; acc1[5] += a1*b1.y; acc1[6] += a1*b1.z; acc1[7] += a1*b1.w;
    }
  }
  const int ocb = ocg*64 + wv*16 + og*8;
  float* o0 = pd + (size_t)kc*1048576 + ((size_t)b*128 + ocb)*1024 + (pg*2)*32 + ox;
  float* o1 = o0 + 32;
#pragma unroll
  for (int j = 0; j < 8; ++j) {
    o0[(size_t)j*1024] = acc0[j];
    o1[(size_t)j*1024] = acc1[j];
  }
}

// ---------------- conv2 partial reduce: h = bias + p0 + p1 ----------------
__global__ __launch_bounds__(256) void k_c2red(const float* __restrict__ pd,
    const float* __restrict__ bias, float* __restrict__ h) {
  int i4 = blockIdx.x*256 + threadIdx.x;
  int oc = (i4 >> 8) & 127;
  float bv = bias[oc];
  const float4 p0 = ((const float4*)pd)[i4];
  const float4 p1 = ((const float4*)pd)[i4 + 262144];
  float4 r;
  r.x = bv + p0.x + p1.x; r.y = bv + p0.y + p1.y;
  r.z = bv + p0.z + p1.z; r.w = bv + p0.w + p1.w;
  ((float4*)h)[i4] = r;
}

// ---------------- res 3x3 as implicit GEMM, kc-split x8, prefetched ----------------
__global__ __launch_bounds__(256) void k_res3(const float* __restrict__ h,
    const float* __restrict__ w, float* __restrict__ pd3) {
  __shared__ float A[72*64];
  __shared__ float B[72*64];
  const int b = blockIdx.z, yp = blockIdx.y, kc = blockIdx.x;   // kc 0..7
  const int tid = threadIdx.x, lane = tid & 63;
  const int wv = __builtin_amdgcn_readfirstlane(tid >> 6);
  const int col = lane & 31, og = lane >> 5;
  const int prow = lane >> 5;
  const float* hb = h + (size_t)b*131072;
  const int row0 = yp*2;
  float prA[18];
  float4 prB[5];
#define R3_LOADA(t) { \
    _Pragma("unroll") \
    for (int j = 0; j < 18; ++j) { \
      int k_rel = wv + j*4; \
      int ic_r = k_rel/9, tap = k_rel - ic_r*9; \
      int dy = tap/3, dx = tap - dy*3; \
      int py = row0 + prow + dy - 1, px = col + dx - 1; \
      float v = 0.f; \
      if (((unsigned)py < 32u) && ((unsigned)px < 32u)) \
        v = fmaxf(hb[(size_t)(kc*16 + (t)*8 + ic_r)*1024 + py*32 + px], 0.f); \
      prA[j] = v; \
    } }
#define R3_LOADB(t) { \
    _Pragma("unroll") \
    for (int j = 0; j < 5; ++j) { \
      int rr = wv + j*4; \
      if (rr < 18) \
        prB[j] = *(const float4*)(w + (size_t)lane*1152 + (kc*16 + (t)*8)*9 + rr*4); \
    } }
  R3_LOADA(0) R3_LOADB(0)
  float acc0[8] = {0,0,0,0,0,0,0,0};
  float acc1[8] = {0,0,0,0,0,0,0,0};
  for (int tt = 0; tt < 2; ++tt) {
    __syncthreads();
#pragma unroll
    for (int j = 0; j < 18; ++j) {               // A store: banks = lane%32, 2-way free
      int k_rel = wv + j*4;
      A[k_rel*64 + lane] = prA[j];
    }
#pragma unroll
    for (int j = 0; j < 5; ++j) {                // B store: oc = lane -> conflict-free
      int rr = wv + j*4;
      if (rr < 18) {
        B[(rr*4+0)*64 + lane] = prB[j].x;
        B[(rr*4+1)*64 + lane] = prB[j].y;
        B[(rr*4+2)*64 + lane] = prB[j].z;
        B[(rr*4+3)*64 + lane] = prB[j].w;
      }
    }
    __syncthreads();
    if (tt == 0) { R3_LOADA(1) R3_LOADB(1) }
    const float* ap = A + col;
    const float* bp = B + wv*16 + og*8;
#pragma unroll 8
    for (int k = 0; k < 72; ++k) {
      float a0 = ap[k*64];
      float a1 = ap[k*64 + 32];
      float4 b0 = *(const float4*)(bp + k*64);
      float4 b1 = *(const float4*)(bp + k*64 + 4);
      acc0[0] += a0*b0.x; acc0[1] += a0*b0.y; acc0[2] += a0*b0.z; acc0[3] += a0*b0.w;
      acc0[4] += a0*b1.x; acc0[5] += a0*b1.y; acc0[6] += a0*b1.z; acc0[7] += a0*b1.w;
      acc1[0] += a1*b0.x; acc1[1] += a1*b0.y; acc1[2] += a1*b0.z; acc1[3] += a1*b0.w;
      acc1[4] += a1*b1.x; acc1[5] += a1*b1.y; acc1[6] += a1*b1.z; acc1[7] += a1*b1.w;
    }
  }
  const int ocb = wv*16 + og*8;
  float* o0 = pd3 + (size_t)kc*524288 + ((size_t)b*64 + ocb)*1024 + row0*32 + col;
#pragma unroll
  for (int j = 0; j < 8; ++j) {
    o0[(size_t)j*1024]      = acc0[j];
    o0[(size_t)j*1024 + 32] = acc1[j];
  }
}

// ---------------- res3 partial reduce: r1 = sum of 8 kc-partials ----------------
__global__ __launch_bounds__(256) void k_r3red(const float* __restrict__ pd3,
    float* __restrict__ r1) {
  int i4 = blockIdx.x*256 + threadIdx.x;         // 131072 float4s
  float4 s = ((const float4*)pd3)[i4];
#pragma unroll
  for (int c = 1; c < 8; ++c) {
    float4 p = ((const float4*)pd3)[i4 + c*131072];
    s.x += p.x; s.y += p.y; s.z += p.z; s.w += p.w;
  }
  ((float4*)r1)[i4] = s;
}

// ---------------- res 1x1: h += w2 @ relu(r1), 64->128 ----------------
__global__ __launch_bounds__(256) void k_res1(const float* __restrict__ r1,
    const float* __restrict__ w, float* __restrict__ h) {
  __shared__ float B[64*8];
  const int og = blockIdx.y;
  const int tid = threadIdx.x;
#pragma unroll
  for (int j = 0; j < 2; ++j) {
    int f = tid + j*256;                         // 512 floats
    int ocj = f >> 6, ic = f & 63;
    B[ic*8 + ocj] = w[(size_t)(og*8 + ocj)*64 + ic];
  }
  __syncthreads();
  const int p = blockIdx.x*256 + tid;
  const int b = p >> 10, rem = p & 1023;
  const float* rb = r1 + (size_t)b*65536 + rem;
  float acc[8] = {0,0,0,0,0,0,0,0};
  for (int ic = 0; ic < 64; ++ic) {
    float rv = fmaxf(rb[(size_t)ic*1024], 0.f);
    float4 w0 = *(const float4*)&B[ic*8];
    float4 w1 = *(const float4*)&B[ic*8 + 4];
    acc[0] += w0.x*rv; acc[1] += w0.y*rv; acc[2] += w0.z*rv; acc[3] += w0.w*rv;
    acc[4] += w1.x*rv; acc[5] += w1.y*rv; acc[6] += w1.z*rv; acc[7] += w1.w*rv;
  }
  float* hb = h + ((size_t)b*128 + og*8)*1024 + rem;
#pragma unroll
  for (int j = 0; j < 8; ++j) hb[(size_t)j*1024] += acc[j];
}

// ---------------- preq: z_e = pw @ relu(h) + pb, 128->64 ----------------
__global__ __launch_bounds__(256) void k_preq(const float* __restrict__ h,
    const float* __restrict__ w, const float* __restrict__ bias,
    float* __restrict__ ze) {
  __shared__ float B[128*4];
  const int eg = blockIdx.y;
  const int tid = threadIdx.x;
#pragma unroll
  for (int j = 0; j < 2; ++j) {
    int f = tid + j*256;                         // 512 floats
    int ej = f >> 7, ic = f & 127;
    B[ic*4 + ej] = w[(size_t)(eg*4 + ej)*128 + ic];
  }
  __syncthreads();
  const int p = blockIdx.x*256 + tid;
  const int b = p >> 10, rem = p & 1023;
  const float* hb = h + (size_t)b*131072 + rem;
  float acc[4] = {0,0,0,0};
  for (int ic = 0; ic < 128; ++ic) {
    float hv = fmaxf(hb[(size_t)ic*1024], 0.f);
    float4 wv4 = *(const float4*)&B[ic*4];
    acc[0] += wv4.x*hv; acc[1] += wv4.y*hv; acc[2] += wv4.z*hv; acc[3] += wv4.w*hv;
  }
#pragma unroll
  for (int j = 0; j < 4; ++j)
    ze[((size_t)b*64 + eg*4+j)*1024 + rem] = acc[j] + bias[eg*4+j];
}

// ---------------- e2[e] = ||emb_e||^2 ----------------
__global__ __launch_bounds__(256) void k_e2(const float* __restrict__ emb,
                                            float* __restrict__ e2) {
  int e = blockIdx.x*256 + threadIdx.x;
  const float* er = emb + (size_t)e*64;
  float s = 0.f;
#pragma unroll
  for (int i = 0; i < 16; ++i) {
    float4 v = *(const float4*)(er + i*4);
    s += v.x*v.x + v.y*v.y + v.z*v.z + v.w*v.w;
  }
  e2[e] = s;
}

// ---------------- VQ distances + per-strip argmin ----------------
__global__ __launch_bounds__(256) void k_vq(const float* __restrict__ ze,
    const float* __restrict__ emb, const float* __restrict__ e2,
    float* __restrict__ part_d, int* __restrict__ part_i) {
  const int bid = blockIdx.x;
  const int sg = bid & 15, pg = bid >> 4;
  const int tid = threadIdx.x, lane = tid & 63;
  const int wv = __builtin_amdgcn_readfirstlane(tid >> 6);
  const int s = sg*4 + wv;
  const int p = pg*64 + lane;
  const int b = p >> 10, rem = p & 1023;
  const float* zb = ze + (size_t)b*64*1024 + rem;
  float z[64];
#pragma unroll
  for (int i = 0; i < 64; ++i) z[i] = zb[(size_t)i*1024];
  float best = 3.4e38f; int bi = 0;
  const float* es = emb + (size_t)s*16*64;
  for (int j4 = 0; j4 < 16; j4 += 4) {
    float a0 = 0.f, a1 = 0.f, a2 = 0.f, a3 = 0.f;
#pragma unroll
    for (int i = 0; i < 64; ++i) {
      float zi = z[i];
      a0 += es[(j4+0)*64+i]*zi;
      a1 += es[(j4+1)*64+i]*zi;
      a2 += es[(j4+2)*64+i]*zi;
      a3 += es[(j4+3)*64+i]*zi;
    }
    float d0 = e2[s*16+j4+0] - 2.f*a0;
    float d1 = e2[s*16+j4+1] - 2.f*a1;
    float d2 = e2[s*16+j4+2] - 2.f*a2;
    float d3 = e2[s*16+j4+3] - 2.f*a3;
    if (d0 < best) { best = d0; bi = s*16+j4+0; }
    if (d1 < best) { best = d1; bi = s*16+j4+1; }
    if (d2 < best) { best = d2; bi = s*16+j4+2; }
    if (d3 < best) { best = d3; bi = s*16+j4+3; }
  }
  part_d[(size_t)s*NPOS + p] = best;
  part_i[(size_t)s*NPOS + p] = bi;
}

// ---------------- final argmin + z_q + loss partials + counts + idx ----------------
__global__ __launch_bounds__(256) void k_reduce(const float* __restrict__ part_d,
    const int* __restrict__ part_i, const float* __restrict__ emb,
    const float* __restrict__ ze, float* __restrict__ out,
    int* __restrict__ counts, float* __restrict__ sse) {
  const int p = blockIdx.x*256 + threadIdx.x;
  float best = 3.4e38f; int id = 0;
  for (int s = 0; s < 64; ++s) {
    float d = part_d[(size_t)s*NPOS + p];
    int   i = part_i[(size_t)s*NPOS + p];
    if (d < best) { best = d; id = i; }
  }
  out[IDX_OFF + p] = (float)id;
  atomicAdd(&counts[id], 1);
  const int b = p >> 10, rem = p & 1023;
  const float* zb = ze + (size_t)b*64*1024 + rem;
  float* qo = out + ZQ_OFF + (size_t)b*64*1024 + rem;
  const float* er = emb + (size_t)id*64;
  float local = 0.f;
#pragma unroll
  for (int e4 = 0; e4 < 16; ++e4) {
    float4 q = *(const float4*)(er + e4*4);
    float z0 = zb[(size_t)(e4*4+0)*1024];
    float z1 = zb[(size_t)(e4*4+1)*1024];
    float z2 = zb[(size_t)(e4*4+2)*1024];
    float z3 = zb[(size_t)(e4*4+3)*1024];
    qo[(size_t)(e4*4+0)*1024] = q.x;
    qo[(size_t)(e4*4+1)*1024] = q.y;
    qo[(size_t)(e4*4+2)*1024] = q.z;
    qo[(size_t)(e4*4+3)*1024] = q.w;
    float d0 = q.x - z0, d1 = q.y - z1, d2 = q.z - z2, d3 = q.w - z3;
    local += d0*d0 + d1*d1 + d2*d2 + d3*d3;
  }
  for (int off = 32; off; off >>= 1) local += __shfl_down(local, off);
  if ((threadIdx.x & 63) == 0) atomicAdd(sse, local);
}

// ---------------- scalars: loss & perplexity ----------------
__global__ __launch_bounds__(256) void k_final(const int* __restrict__ counts,
    const float* __restrict__ sse, float* __restrict__ out) {
  __shared__ float red[4];
  float part = 0.f;
  for (int e = threadIdx.x; e < 1024; e += 256) {
    float pm = (float)counts[e] * (1.f/8192.f);
    part += pm * logf(pm + 1e-10f);
  }
  for (int off = 32; off; off >>= 1) part += __shfl_down(part, off);
  if ((threadIdx.x & 63) == 0) red[threadIdx.x >> 6] = part;
  __syncthreads();
  if (threadIdx.x == 0) {
    float t = red[0] + red[1] + red[2] + red[3];
    out[PPL_OFF] = expf(-t);
    out[0] = 1.25f * sse[0] * (1.f/524288.f);
  }
}

// ---------------- launcher ----------------
extern "C" void kernel_launch(void* const* d_in, const int* in_sizes, int n_in,
                              void* d_out, int out_size, void* d_ws, size_t ws_size,
                              hipStream_t stream) {
  (void)in_sizes; (void)n_in; (void)out_size; (void)ws_size;
  const float* x   = (const float*)d_in[0];
  const float* w1  = (const float*)d_in[1];
  const float* b1  = (const float*)d_in[2];
  const float* w2  = (const float*)d_in[3];
  const float* b2  = (const float*)d_in[4];
  const float* rw1 = (const float*)d_in[5];
  const float* rw2 = (const float*)d_in[6];
  const float* pw  = (const float*)d_in[7];
  const float* pb  = (const float*)d_in[8];
  const float* emb = (const float*)d_in[9];
  float* out = (float*)d_out;
  char* ws = (char*)d_ws;
  // layout (total 46,145,540 B):
  // [0,32MB)  h1 (conv1->conv2p), then REUSED as pd3 [0,16MB) (res3->r3red)
  float* h1     = (float*)(ws);
  float* pd3    = (float*)(ws);                    // res3 partials (8x2MB), h1 dead
  float* c2pd   = (float*)(ws + 33554432);         // conv2 partials [32,40MB)
  float* r1     = (float*)(ws + 33554432);         // reuse after c2red [32,34MB)
  float* ze     = (float*)(ws + 35651584);         // [34,36MB)
  float* pd     = (float*)(ws + 37748736);         // VQ partial dist [36,38MB)
  int*   pi     = (int*)  (ws + 39845888);         // VQ partial idx  [38,40MB)
  float* h      = (float*)(ws + 41943040);         // [40,44MB)
  float* e2     = (float*)(ws + 46137344);
  int*   counts = (int*)  (ws + 46141440);
  float* sse    = (float*)(ws + 46145536);

  hipMemsetAsync(counts, 0, 1024*4 + 4, stream);
  k_conv1<<<dim3(2,128,8), 256, 0, stream>>>(x, w1, b1, h1);
  k_conv2p<<<dim3(4,16,8), 256, 0, stream>>>(h1, w2, c2pd);
  k_c2red<<<1024, 256, 0, stream>>>(c2pd, b2, h);
  for (int it = 0; it < 2; ++it) {
    k_res3<<<dim3(8,16,8), 256, 0, stream>>>(h, rw1, pd3);
    k_r3red<<<512, 256, 0, stream>>>(pd3, r1);
    k_res1<<<dim3(32,16), 256, 0, stream>>>(r1, rw2, h);
  }
  k_preq<<<dim3(32,16), 256, 0, stream>>>(h, pw, pb, ze);
  k_e2<<<4, 256, 0, stream>>>(emb, e2);
  k_vq<<<2048, 256, 0, stream>>>(ze, emb, e2, pd, pi);
  k_reduce<<<32, 256, 0, stream>>>(pd, pi, emb, ze, out, counts, sse);
  k_final<<<1, 256, 0, stream>>>(counts, sse, out);
  hipMemcpyAsync(out + EMB_OFF, emb, 65536*4, hipMemcpyDeviceToDevice, stream);
}